// Round 1
// baseline (445.311 us; speedup 1.0000x reference)
//
#include <hip/hip_runtime.h>
#include <cmath>

#define LL   4096
#define HWD  64
#define CCH  96
#define QQ   24
#define DDI  192
#define NST  16
#define NCH  32      // chunks in scan
#define CLEN 128     // steps per chunk
#define TSC  64      // B/C LDS tile steps

// ---------------- workspace layout (floats) ----------------
static const size_t OFF_F   = 0;          // 786432  f (concat arf) -> reused as edge
static const size_t OFF_H   = 786432;     // 786432  h
static const size_t OFF_E   = 1572864;    // 196608  e (raw)
static const size_t OFF_BN  = 1769472;    // 64      bn scale[24], shift[24]
static const size_t OFF_S1  = 1769536;    // 192
static const size_t OFF_W1  = 1769728;    // 192
static const size_t OFF_S2  = 1769920;    // 192
static const size_t OFF_W2  = 1770112;    // 192
static const size_t OFF_HN  = 1770304;    // 786432  hn (B,L,96)
static const size_t OFF_XM  = 2556736;    // 1572864 xm (B,L,192) -> reused as g
static const size_t OFF_Z   = 4129600;    // 1572864 z  (B,L,192)
static const size_t OFF_XC  = 5702464;    // 1572864 xc (B,L,192)
static const size_t OFF_DTS = 7275328;    // 6291456 dts (B,K,L,192)
static const size_t OFF_BC  = 13566784;   // 1048576 B|C (B,K,L,32)
static const size_t OFF_YK  = 14615360;   // 6291456 yk (B,K,L,192) at hw position
static const size_t OFF_HL  = 20906816;   // 786432  chunk-local final states
static const size_t OFF_SD  = 21693248;   // 49152   per-chunk sum(dt)
static const size_t OFF_HIN = 21742400;   // 786432  chunk incoming states
static const size_t OFF_Y2  = 22528832;   // 786432  y2 (B,96,L)

static __device__ __forceinline__ int map_k(int k, int l) {
  int ll = (k & 2) ? (LL - 1 - l) : l;
  return (k & 1) ? (((ll & 63) << 6) | (ll >> 6)) : ll;
}

// ---------------- K1: ARF grouped dilated convs (concat f1..f4) ----------------
__global__ __launch_bounds__(256) void k_arf(const float* __restrict__ x,
    const float* __restrict__ w1, const float* __restrict__ b1,
    const float* __restrict__ w2, const float* __restrict__ b2,
    const float* __restrict__ w3, const float* __restrict__ b3,
    const float* __restrict__ w4, const float* __restrict__ b4,
    float* __restrict__ f) {
  int idx = blockIdx.x * 256 + threadIdx.x;            // B*96*L
  int p = idx & (LL - 1);
  int oc = (idx >> 12) % CCH;
  int b  = idx / (CCH * LL);
  int i = oc / QQ, q = oc % QQ;
  int dil = 1 << i;
  const float* w  = (i == 0 ? w1 : i == 1 ? w2 : i == 2 ? w3 : w4) + q * 36;
  const float* bb = (i == 0 ? b1 : i == 1 ? b2 : i == 2 ? b3 : b4);
  int yy0 = p >> 6, xx0 = p & 63;
  float acc = bb[q];
  const float* xin = x + ((size_t)b * CCH + q * 4) * LL;
  #pragma unroll
  for (int ky = 0; ky < 3; ky++) {
    int yy = yy0 + (ky - 1) * dil;
    if (yy < 0 || yy >= HWD) continue;
    #pragma unroll
    for (int kx = 0; kx < 3; kx++) {
      int xx = xx0 + (kx - 1) * dil;
      if (xx < 0 || xx >= HWD) continue;
      int pp = (yy << 6) + xx;
      #pragma unroll
      for (int ci = 0; ci < 4; ci++)
        acc += w[ci * 9 + ky * 3 + kx] * xin[(size_t)ci * LL + pp];
    }
  }
  f[idx] = acc;
}

// ---------------- K2: fuse 1x1 (96->96) ----------------
__global__ __launch_bounds__(256) void k_fuse(const float* __restrict__ f,
    const float* __restrict__ fw, const float* __restrict__ fb, float* __restrict__ h) {
  int idx = blockIdx.x * 256 + threadIdx.x;
  int p = idx & (LL - 1);
  int o = (idx >> 12) % CCH;
  int b = idx / (CCH * LL);
  const float* fr = f + (size_t)b * CCH * LL + p;
  const float* wr = fw + o * CCH;
  float acc = fb[o];
  for (int c = 0; c < CCH; c++) acc += wr[c] * fr[(size_t)c * LL];
  h[idx] = acc;
}

// ---------------- K3: depthwise 3x3 (edge) ----------------
__global__ __launch_bounds__(256) void k_edge(const float* __restrict__ h,
    const float* __restrict__ ew, float* __restrict__ edge) {
  int idx = blockIdx.x * 256 + threadIdx.x;
  int p = idx & (LL - 1);
  int c = (idx >> 12) % CCH;
  int b = idx / (CCH * LL);
  int yy0 = p >> 6, xx0 = p & 63;
  const float* w = ew + c * 9;
  const float* hr = h + ((size_t)b * CCH + c) * LL;
  float acc = 0.f;
  #pragma unroll
  for (int ky = 0; ky < 3; ky++) {
    int yy = yy0 + ky - 1;
    if (yy < 0 || yy >= HWD) continue;
    #pragma unroll
    for (int kx = 0; kx < 3; kx++) {
      int xx = xx0 + kx - 1;
      if (xx < 0 || xx >= HWD) continue;
      acc += w[ky * 3 + kx] * hr[(yy << 6) + xx];
    }
  }
  edge[idx] = acc;
}

// ---------------- K4: 1x1 96->24 ----------------
__global__ __launch_bounds__(256) void k_e1(const float* __restrict__ edge,
    const float* __restrict__ w, const float* __restrict__ bias, float* __restrict__ e) {
  int idx = blockIdx.x * 256 + threadIdx.x;         // B*24*L
  int p = idx & (LL - 1);
  int q = (idx >> 12) % QQ;
  int b = idx / (QQ * LL);
  const float* er = edge + (size_t)b * CCH * LL + p;
  const float* wr = w + q * CCH;
  float acc = bias[q];
  for (int c = 0; c < CCH; c++) acc += wr[c] * er[(size_t)c * LL];
  e[idx] = acc;
}

// ---------------- K5: BN stats over (B,H,W) per channel ----------------
__global__ __launch_bounds__(256) void k_bnstats(const float* __restrict__ e,
    const float* __restrict__ g, const float* __restrict__ bb, float* __restrict__ bn) {
  int q = blockIdx.x, tid = threadIdx.x;
  __shared__ float rs[256], r2[256];
  float s = 0.f, s2 = 0.f;
  for (int b = 0; b < 2; b++) {
    const float* er = e + ((size_t)b * QQ + q) * LL;
    for (int p = tid; p < LL; p += 256) { float v = er[p]; s += v; s2 += v * v; }
  }
  rs[tid] = s; r2[tid] = s2; __syncthreads();
  for (int st = 128; st > 0; st >>= 1) {
    if (tid < st) { rs[tid] += rs[tid + st]; r2[tid] += r2[tid + st]; }
    __syncthreads();
  }
  if (tid == 0) {
    float mu = rs[0] / (2.f * LL);
    float var = r2[0] / (2.f * LL) - mu * mu;
    float sc = g[q] * rsqrtf(var + 1e-5f);
    bn[q] = sc;
    bn[QQ + q] = bb[q] - mu * sc;
  }
}

// ---------------- K6: enh 1x1 24->96, sigmoid gate, h *= (1+sig) ----------------
__global__ __launch_bounds__(256) void k_enh(const float* __restrict__ e,
    const float* __restrict__ bn, const float* __restrict__ w2,
    const float* __restrict__ b2, float* __restrict__ h) {
  int idx = blockIdx.x * 256 + threadIdx.x;
  int p = idx & (LL - 1);
  int o = (idx >> 12) % CCH;
  int b = idx / (CCH * LL);
  const float* er = e + (size_t)b * QQ * LL + p;
  const float* wr = w2 + o * QQ;
  float acc = b2[o];
  #pragma unroll
  for (int q = 0; q < QQ; q++) {
    float en = fmaxf(er[(size_t)q * LL] * bn[q] + bn[QQ + q], 0.f);
    acc += wr[q] * en;
  }
  float sig = 1.f / (1.f + __expf(-acc));
  h[idx] *= (1.f + sig);
}

// ---------------- K7a: per-(b,c) mean+max over L ----------------
__global__ __launch_bounds__(256) void k_rowreduce(const float* __restrict__ t, float* __restrict__ sout) {
  int row = blockIdx.x, tid = threadIdx.x;   // row = b*96+c
  __shared__ float rs[256], rm[256];
  float s = 0.f, m = -3.402823466e38f;
  const float* tr = t + (size_t)row * LL;
  for (int p = tid; p < LL; p += 256) { float v = tr[p]; s += v; m = fmaxf(m, v); }
  rs[tid] = s; rm[tid] = m; __syncthreads();
  for (int st = 128; st > 0; st >>= 1) {
    if (tid < st) { rs[tid] += rs[tid + st]; rm[tid] = fmaxf(rm[tid], rm[tid + st]); }
    __syncthreads();
  }
  if (tid == 0) sout[row] = rs[0] / (float)LL + rm[0];
}

// ---------------- K7b: channel-recal tiny FC ----------------
__global__ __launch_bounds__(128) void k_recal_fc(const float* __restrict__ s1,
    const float* __restrict__ fc1, const float* __restrict__ fc2, float* __restrict__ wout) {
  int b = blockIdx.x, tid = threadIdx.x;
  __shared__ float sv[CCH];
  __shared__ float hid[QQ];
  if (tid < CCH) sv[tid] = s1[b * CCH + tid];
  __syncthreads();
  if (tid < QQ) {
    float a = 0.f;
    for (int c = 0; c < CCH; c++) a += sv[c] * fc1[tid * CCH + c];
    hid[tid] = fmaxf(a, 0.f);
  }
  __syncthreads();
  if (tid < CCH) {
    float a = 0.f;
    #pragma unroll
    for (int q = 0; q < QQ; q++) a += hid[q] * fc2[tid * QQ + q];
    wout[b * CCH + tid] = 1.f / (1.f + __expf(-a));
  }
}

// ---------------- K8a: apply recal + LayerNorm(C=96) -> hn (B,L,96) ----------------
__global__ __launch_bounds__(128) void k_recal_ln(const float* __restrict__ h,
    const float* __restrict__ w1buf, const float* __restrict__ ng,
    const float* __restrict__ nb, float* __restrict__ hn) {
  int pb = blockIdx.x;                 // b*L+p
  int b = pb >> 12, p = pb & (LL - 1);
  int tid = threadIdx.x;
  __shared__ float red[128];
  __shared__ float smu, srs;
  float v = 0.f;
  if (tid < CCH) v = h[((size_t)b * CCH + tid) * LL + p] * w1buf[b * CCH + tid];
  red[tid] = v; __syncthreads();
  for (int s = 64; s > 0; s >>= 1) { if (tid < s) red[tid] += red[tid + s]; __syncthreads(); }
  if (tid == 0) smu = red[0] / (float)CCH;
  __syncthreads();
  float xcv = (tid < CCH) ? v - smu : 0.f;
  red[tid] = xcv * xcv; __syncthreads();
  for (int s = 64; s > 0; s >>= 1) { if (tid < s) red[tid] += red[tid + s]; __syncthreads(); }
  if (tid == 0) srs = rsqrtf(red[0] / (float)CCH + 1e-5f);
  __syncthreads();
  if (tid < CCH) hn[((size_t)b * LL + p) * CCH + tid] = xcv * srs * ng[tid] + nb[tid];
}

// ---------------- K8b: in_proj (96 -> 384), split xm/z ----------------
__global__ __launch_bounds__(384) void k_inproj(const float* __restrict__ hn,
    const float* __restrict__ W, float* __restrict__ xm, float* __restrict__ z) {
  int pix0 = blockIdx.x * 16;          // over B*L
  int tid = threadIdx.x;
  __shared__ float a[16][CCH];
  for (int t = tid; t < 16 * CCH; t += 384) a[t / CCH][t % CCH] = hn[(size_t)pix0 * CCH + t];
  __syncthreads();
  const float* wr = W + tid * CCH;
  float acc[16];
  #pragma unroll
  for (int j = 0; j < 16; j++) acc[j] = 0.f;
  for (int c = 0; c < CCH; c += 4) {
    float4 wv = *(const float4*)(wr + c);
    #pragma unroll
    for (int j = 0; j < 16; j++) {
      float4 av = *(const float4*)(&a[j][c]);
      acc[j] = fmaf(av.x, wv.x, fmaf(av.y, wv.y, fmaf(av.z, wv.z, fmaf(av.w, wv.w, acc[j]))));
    }
  }
  float* dst = (tid < DDI) ? xm : z;
  int oo = (tid < DDI) ? tid : tid - DDI;
  #pragma unroll
  for (int j = 0; j < 16; j++) dst[(size_t)(pix0 + j) * DDI + oo] = acc[j];
}

// ---------------- K9: depthwise 3x3 on xm + bias + silu -> xc ----------------
__global__ __launch_bounds__(256) void k_ssconv(const float* __restrict__ xm,
    const float* __restrict__ w, const float* __restrict__ bias, float* __restrict__ xc) {
  int idx = blockIdx.x * 256 + threadIdx.x;      // B*L*192, d fastest
  int d = idx % DDI;
  int p = (idx / DDI) & (LL - 1);
  int b = idx / (DDI * LL);
  int yy0 = p >> 6, xx0 = p & 63;
  float acc = bias[d];
  const float* wr = w + d * 9;
  const float* xr = xm + (size_t)b * LL * DDI + d;
  #pragma unroll
  for (int ky = 0; ky < 3; ky++) {
    int yy = yy0 + ky - 1;
    if (yy < 0 || yy >= HWD) continue;
    #pragma unroll
    for (int kx = 0; kx < 3; kx++) {
      int xx = xx0 + kx - 1;
      if (xx < 0 || xx >= HWD) continue;
      acc += wr[ky * 3 + kx] * xr[(size_t)((yy << 6) + xx) * DDI];
    }
  }
  xc[(size_t)idx] = acc / (1.f + __expf(-acc));
}

// ---------------- K10: x_proj (192->38) + dt proj (6->192) + softplus ----------------
__global__ __launch_bounds__(256) void k_xdbl(const float* __restrict__ xc,
    const float* __restrict__ xpw, const float* __restrict__ dtw,
    const float* __restrict__ dtb, float* __restrict__ dts, float* __restrict__ bcb) {
  int lt = blockIdx.x;                 // L/8 tiles
  int bk = blockIdx.y;                 // b*4+k
  int b = bk >> 2, k = bk & 3;
  int tid = threadIdx.x;
  __shared__ float xs[8][DDI];
  __shared__ float dtr[8][6];
  for (int t = tid; t < 8 * DDI; t += 256) {
    int li = t / DDI, dd = t % DDI;
    xs[li][dd] = xc[((size_t)b * LL + map_k(k, lt * 8 + li)) * DDI + dd];
  }
  __syncthreads();
  for (int task = tid; task < 8 * 38; task += 256) {
    int li = task / 38, c = task % 38;
    const float4* w4 = (const float4*)(xpw + (size_t)(k * 38 + c) * DDI);
    const float4* x4 = (const float4*)(&xs[li][0]);
    float acc = 0.f;
    #pragma unroll 8
    for (int dd = 0; dd < DDI / 4; dd++) {
      float4 a4 = w4[dd], b4 = x4[dd];
      acc += a4.x * b4.x + a4.y * b4.y + a4.z * b4.z + a4.w * b4.w;
    }
    if (c < 6) dtr[li][c] = acc;
    else bcb[((size_t)bk * LL + lt * 8 + li) * 32 + (c - 6)] = acc;
  }
  __syncthreads();
  for (int task = tid; task < 8 * DDI; task += 256) {
    int li = task / DDI, dd = task % DDI;
    float acc = dtb[k * DDI + dd];
    const float* wr = dtw + (size_t)(k * DDI + dd) * 6;
    #pragma unroll
    for (int r = 0; r < 6; r++) acc += wr[r] * dtr[li][r];
    float sp = (acc > 20.f) ? acc : log1pf(__expf(acc));
    dts[((size_t)bk * LL + lt * 8 + li) * DDI + dd] = sp;
  }
}

// ---------------- K11: chunked selective scan ----------------
template <int PASS>
__global__ __launch_bounds__(192) void k_scan(const float* __restrict__ dts,
    const float* __restrict__ bcb, const float* __restrict__ xc,
    const float* __restrict__ A_logs, float* __restrict__ hl, float* __restrict__ sd,
    const float* __restrict__ hin, float* __restrict__ yk) {
  int ch = blockIdx.x, bk = blockIdx.y;
  int b = bk >> 2, k = bk & 3;
  int d = threadIdx.x;
  float Av[NST];
  #pragma unroll
  for (int n = 0; n < NST; n++) Av[n] = -__expf(A_logs[(size_t)(k * DDI + d) * NST + n]);
  bool pw = true;
  #pragma unroll
  for (int n = 1; n < NST; n++) pw = pw && (fabsf(Av[n] - (float)(n + 1) * Av[0]) <= 1e-3f * (n + 1));
  float h[NST];
  if (PASS == 0) {
    #pragma unroll
    for (int n = 0; n < NST; n++) h[n] = 0.f;
  } else {
    const float* hp = hin + ((size_t)(bk * DDI + d) * NCH + ch) * NST;
    #pragma unroll
    for (int n = 0; n < NST; n++) h[n] = hp[n];
  }
  float sumdt = 0.f;
  __shared__ float bcs[TSC][32];
  int l0 = ch * CLEN;
  for (int t0 = 0; t0 < CLEN; t0 += TSC) {
    __syncthreads();
    for (int t = d; t < TSC * 32; t += 192)
      bcs[t >> 5][t & 31] = bcb[((size_t)bk * LL + l0 + t0 + (t >> 5)) * 32 + (t & 31)];
    __syncthreads();
    for (int tt = 0; tt < TSC; tt++) {
      int l = l0 + t0 + tt;
      float dt = dts[((size_t)bk * LL + l) * DDI + d];
      int p = map_k(k, l);
      float u = xc[((size_t)b * LL + p) * DDI + d];
      float dtu = dt * u;
      if (PASS == 0) sumdt += dt;
      float eA[NST];
      if (pw) {
        float E = __expf(dt * Av[0]);
        float en = 1.f;
        #pragma unroll
        for (int n = 0; n < NST; n++) { en *= E; eA[n] = en; }
      } else {
        #pragma unroll
        for (int n = 0; n < NST; n++) eA[n] = __expf(dt * Av[n]);
      }
      float y = 0.f;
      #pragma unroll
      for (int n = 0; n < NST; n++) {
        h[n] = eA[n] * h[n] + dtu * bcs[tt][n];
        y += h[n] * bcs[tt][16 + n];
      }
      if (PASS == 1) yk[((size_t)bk * LL + p) * DDI + d] = y;
    }
  }
  if (PASS == 0) {
    float* hp = hl + ((size_t)(bk * DDI + d) * NCH + ch) * NST;
    #pragma unroll
    for (int n = 0; n < NST; n++) hp[n] = h[n];
    sd[(size_t)(bk * DDI + d) * NCH + ch] = sumdt;
  }
}

// ---------------- K11b: chunk-carry propagation ----------------
__global__ __launch_bounds__(256) void k_carry(const float* __restrict__ A_logs,
    const float* __restrict__ hl, const float* __restrict__ sd, float* __restrict__ hin) {
  int idx = blockIdx.x * 256 + threadIdx.x;  // 8*192*16
  int n = idx & 15;
  int d = (idx >> 4) % DDI;
  int bk = idx / (DDI * NST);
  int k = bk & 3;
  float Aval = -__expf(A_logs[(size_t)(k * DDI + d) * NST + n]);
  float h = 0.f;
  size_t base = (size_t)(bk * DDI + d) * NCH;
  for (int ch = 0; ch < NCH; ch++) {
    hin[(base + ch) * NST + n] = h;
    h = __expf(Aval * sd[base + ch]) * h + hl[(base + ch) * NST + n];
  }
}

// ---------------- K12a: combine 4 dirs + D*u + LN(192) + silu(z) -> g ----------------
__global__ __launch_bounds__(192) void k_combine(const float* __restrict__ yk,
    const float* __restrict__ xc, const float* __restrict__ Ds, const float* __restrict__ z,
    const float* __restrict__ ong, const float* __restrict__ onb, float* __restrict__ g) {
  int pb = blockIdx.x;
  int b = pb >> 12, p = pb & (LL - 1);
  int d = threadIdx.x;
  __shared__ float red[DDI];
  __shared__ float smu, srs;
  size_t base = ((size_t)b * 4 * LL + p) * DDI + d;
  float v = yk[base] + yk[base + (size_t)LL * DDI] + yk[base + 2ul * LL * DDI] + yk[base + 3ul * LL * DDI];
  v += (Ds[d] + Ds[DDI + d] + Ds[2 * DDI + d] + Ds[3 * DDI + d]) * xc[((size_t)b * LL + p) * DDI + d];
  red[d] = v; __syncthreads();
  if (d < 64) red[d] += red[d + 128];
  __syncthreads();
  for (int s = 64; s > 0; s >>= 1) { if (d < s) red[d] += red[d + s]; __syncthreads(); }
  if (d == 0) smu = red[0] / (float)DDI;
  __syncthreads();
  float xcv = v - smu;
  red[d] = xcv * xcv; __syncthreads();
  if (d < 64) red[d] += red[d + 128];
  __syncthreads();
  for (int s = 64; s > 0; s >>= 1) { if (d < s) red[d] += red[d + s]; __syncthreads(); }
  if (d == 0) srs = rsqrtf(red[0] / (float)DDI + 1e-5f);
  __syncthreads();
  float yv = xcv * srs * ong[d] + onb[d];
  float zz = z[((size_t)b * LL + p) * DDI + d];
  g[((size_t)b * LL + p) * DDI + d] = yv * (zz / (1.f + __expf(-zz)));
}

// ---------------- K12b: out_proj (192 -> 96) -> y2 (B,96,L) ----------------
__global__ __launch_bounds__(192) void k_outproj(const float* __restrict__ g,
    const float* __restrict__ W, float* __restrict__ y2) {
  int pix0 = blockIdx.x * 32;          // over B*L
  int b = pix0 / LL, p0 = pix0 & (LL - 1);
  int tid = threadIdx.x;
  __shared__ float a[32][DDI];
  for (int t = tid; t < 32 * DDI; t += 192) a[t / DDI][t % DDI] = g[(size_t)pix0 * DDI + t];
  __syncthreads();
  int o = tid % CCH, ph = tid / CCH;
  const float* wr = W + o * DDI;
  float acc[16];
  #pragma unroll
  for (int j = 0; j < 16; j++) acc[j] = 0.f;
  for (int c = 0; c < DDI; c += 4) {
    float4 wv = *(const float4*)(wr + c);
    #pragma unroll
    for (int j = 0; j < 16; j++) {
      float4 av = *(const float4*)(&a[ph * 16 + j][c]);
      acc[j] = fmaf(av.x, wv.x, fmaf(av.y, wv.y, fmaf(av.z, wv.z, fmaf(av.w, wv.w, acc[j]))));
    }
  }
  float* base = y2 + ((size_t)b * CCH + o) * LL + p0 + ph * 16;
  #pragma unroll
  for (int jj = 0; jj < 4; jj++)
    *(float4*)(base + jj * 4) = make_float4(acc[jj * 4], acc[jj * 4 + 1], acc[jj * 4 + 2], acc[jj * 4 + 3]);
}

// ---------------- K14: recal-apply + proj 1x1 + residual ----------------
__global__ __launch_bounds__(256) void k_final(const float* __restrict__ x,
    const float* __restrict__ y2, const float* __restrict__ w2buf,
    const float* __restrict__ pw, const float* __restrict__ pb, float* __restrict__ out) {
  int idx = blockIdx.x * 256 + threadIdx.x;
  int p = idx & (LL - 1);
  int c = (idx >> 12) % CCH;
  int b = idx / (CCH * LL);
  const float* yr = y2 + (size_t)b * CCH * LL + p;
  const float* wr = pw + c * CCH;
  const float* wc = w2buf + b * CCH;
  float acc = pb[c];
  for (int o = 0; o < CCH; o++) acc += wr[o] * yr[(size_t)o * LL] * wc[o];
  out[idx] = x[idx] + acc;
}

extern "C" void kernel_launch(void* const* d_in, const int* in_sizes, int n_in,
                              void* d_out, int out_size, void* d_ws, size_t ws_size,
                              hipStream_t stream) {
  const float* x        = (const float*)d_in[0];
  const float* arf_w1   = (const float*)d_in[1];
  const float* arf_b1   = (const float*)d_in[2];
  const float* arf_w2   = (const float*)d_in[3];
  const float* arf_b2   = (const float*)d_in[4];
  const float* arf_w3   = (const float*)d_in[5];
  const float* arf_b3   = (const float*)d_in[6];
  const float* arf_w4   = (const float*)d_in[7];
  const float* arf_b4   = (const float*)d_in[8];
  const float* fuse_w   = (const float*)d_in[9];
  const float* fuse_b   = (const float*)d_in[10];
  const float* edge_w   = (const float*)d_in[11];
  const float* enh_w1   = (const float*)d_in[12];
  const float* enh_b1   = (const float*)d_in[13];
  const float* bn_g     = (const float*)d_in[14];
  const float* bn_b     = (const float*)d_in[15];
  const float* enh_w2   = (const float*)d_in[16];
  const float* enh_b2   = (const float*)d_in[17];
  const float* pre_fc1  = (const float*)d_in[18];
  const float* pre_fc2  = (const float*)d_in[19];
  const float* norm_g   = (const float*)d_in[20];
  const float* norm_b   = (const float*)d_in[21];
  const float* in_proj_w= (const float*)d_in[22];
  const float* ss_conv_w= (const float*)d_in[23];
  const float* ss_conv_b= (const float*)d_in[24];
  const float* x_proj_w = (const float*)d_in[25];
  const float* dt_w     = (const float*)d_in[26];
  const float* dt_b     = (const float*)d_in[27];
  const float* A_logs   = (const float*)d_in[28];
  const float* Ds       = (const float*)d_in[29];
  const float* out_ng   = (const float*)d_in[30];
  const float* out_nb   = (const float*)d_in[31];
  const float* out_proj_w = (const float*)d_in[32];
  const float* post_fc1 = (const float*)d_in[33];
  const float* post_fc2 = (const float*)d_in[34];
  const float* proj_w   = (const float*)d_in[35];
  const float* proj_b   = (const float*)d_in[36];

  float* ws = (float*)d_ws;
  float* fbuf  = ws + OFF_F;
  float* hbuf  = ws + OFF_H;
  float* ebuf  = ws + OFF_E;
  float* bnbuf = ws + OFF_BN;
  float* s1buf = ws + OFF_S1;
  float* w1buf = ws + OFF_W1;
  float* s2buf = ws + OFF_S2;
  float* w2buf = ws + OFF_W2;
  float* hnbuf = ws + OFF_HN;
  float* xmbuf = ws + OFF_XM;
  float* zbuf  = ws + OFF_Z;
  float* xcbuf = ws + OFF_XC;
  float* dtsbuf= ws + OFF_DTS;
  float* bcbuf = ws + OFF_BC;
  float* ykbuf = ws + OFF_YK;
  float* hlbuf = ws + OFF_HL;
  float* sdbuf = ws + OFF_SD;
  float* hinbuf= ws + OFF_HIN;
  float* y2buf = ws + OFF_Y2;
  float* gbuf  = xmbuf;   // reuse (xm dead after k_ssconv)

  k_arf<<<3072, 256, 0, stream>>>(x, arf_w1, arf_b1, arf_w2, arf_b2, arf_w3, arf_b3, arf_w4, arf_b4, fbuf);
  k_fuse<<<3072, 256, 0, stream>>>(fbuf, fuse_w, fuse_b, hbuf);
  k_edge<<<3072, 256, 0, stream>>>(hbuf, edge_w, fbuf);   // edge reuses fbuf
  k_e1<<<768, 256, 0, stream>>>(fbuf, enh_w1, enh_b1, ebuf);
  k_bnstats<<<24, 256, 0, stream>>>(ebuf, bn_g, bn_b, bnbuf);
  k_enh<<<3072, 256, 0, stream>>>(ebuf, bnbuf, enh_w2, enh_b2, hbuf);
  k_rowreduce<<<192, 256, 0, stream>>>(hbuf, s1buf);
  k_recal_fc<<<2, 128, 0, stream>>>(s1buf, pre_fc1, pre_fc2, w1buf);
  k_recal_ln<<<8192, 128, 0, stream>>>(hbuf, w1buf, norm_g, norm_b, hnbuf);
  k_inproj<<<512, 384, 0, stream>>>(hnbuf, in_proj_w, xmbuf, zbuf);
  k_ssconv<<<6144, 256, 0, stream>>>(xmbuf, ss_conv_w, ss_conv_b, xcbuf);
  k_xdbl<<<dim3(512, 8), 256, 0, stream>>>(xcbuf, x_proj_w, dt_w, dt_b, dtsbuf, bcbuf);
  k_scan<0><<<dim3(NCH, 8), 192, 0, stream>>>(dtsbuf, bcbuf, xcbuf, A_logs, hlbuf, sdbuf, nullptr, nullptr);
  k_carry<<<96, 256, 0, stream>>>(A_logs, hlbuf, sdbuf, hinbuf);
  k_scan<1><<<dim3(NCH, 8), 192, 0, stream>>>(dtsbuf, bcbuf, xcbuf, A_logs, nullptr, nullptr, hinbuf, ykbuf);
  k_combine<<<8192, 192, 0, stream>>>(ykbuf, xcbuf, Ds, zbuf, out_ng, out_nb, gbuf);
  k_outproj<<<256, 192, 0, stream>>>(gbuf, out_proj_w, y2buf);
  k_rowreduce<<<192, 256, 0, stream>>>(y2buf, s2buf);
  k_recal_fc<<<2, 128, 0, stream>>>(s2buf, post_fc1, post_fc2, w2buf);
  k_final<<<3072, 256, 0, stream>>>(x, y2buf, w2buf, proj_w, proj_b, (float*)d_out);
  (void)in_sizes; (void)n_in; (void)out_size; (void)ws_size;
}

// Round 2
// 381.899 us; speedup vs baseline: 1.1660x; 1.1660x over previous
//
#include <hip/hip_runtime.h>
#include <cmath>

#define LL   4096
#define HWD  64
#define CCH  96
#define QQ   24
#define DDI  192
#define NST  16
#define NCH  32      // chunks in scan
#define CLEN 128     // steps per chunk
#define TSC  64      // B/C LDS tile steps
#define XT   128     // positions per block in k_xdbl

// ---------------- workspace layout (floats) ----------------
static const size_t OFF_F   = 0;          // 786432  f (concat arf) -> reused as edge
static const size_t OFF_H   = 786432;     // 786432  h
static const size_t OFF_E   = 1572864;    // 196608  e (raw)
static const size_t OFF_BN  = 1769472;    // 64      bn scale[24], shift[24]
static const size_t OFF_S1  = 1769536;    // 192
static const size_t OFF_W1  = 1769728;    // 192
static const size_t OFF_S2  = 1769920;    // 192
static const size_t OFF_W2  = 1770112;    // 192
static const size_t OFF_HN  = 1770304;    // 786432  hn (B,L,96)
static const size_t OFF_XM  = 2556736;    // 1572864 xm (B,L,192) -> reused as g
static const size_t OFF_Z   = 4129600;    // 1572864 z  (B,L,192)
static const size_t OFF_XC  = 5702464;    // 1572864 xc (B,L,192)
static const size_t OFF_DTS = 7275328;    // 6291456 dts (B,K,L,192)
static const size_t OFF_BC  = 13566784;   // 1048576 B|C (B,K,L,32)
static const size_t OFF_YK  = 14615360;   // 6291456 yk (B,K,L,192) at hw position
static const size_t OFF_HL  = 20906816;   // 786432  chunk-local final states
static const size_t OFF_SD  = 21693248;   // 49152   per-chunk sum(dt)
static const size_t OFF_HIN = 21742400;   // 786432  chunk incoming states
static const size_t OFF_Y2  = 22528832;   // 786432  y2 (B,96,L)

static __device__ __forceinline__ int map_k(int k, int l) {
  int ll = (k & 2) ? (LL - 1 - l) : l;
  return (k & 1) ? (((ll & 63) << 6) | (ll >> 6)) : ll;
}

// ---------------- K1: ARF grouped dilated convs (concat f1..f4) ----------------
__global__ __launch_bounds__(256) void k_arf(const float* __restrict__ x,
    const float* __restrict__ w1, const float* __restrict__ b1,
    const float* __restrict__ w2, const float* __restrict__ b2,
    const float* __restrict__ w3, const float* __restrict__ b3,
    const float* __restrict__ w4, const float* __restrict__ b4,
    float* __restrict__ f) {
  int idx = blockIdx.x * 256 + threadIdx.x;            // B*96*L
  int p = idx & (LL - 1);
  int oc = (idx >> 12) % CCH;
  int b  = idx / (CCH * LL);
  int i = oc / QQ, q = oc % QQ;
  int dil = 1 << i;
  const float* w  = (i == 0 ? w1 : i == 1 ? w2 : i == 2 ? w3 : w4) + q * 36;
  const float* bb = (i == 0 ? b1 : i == 1 ? b2 : i == 2 ? b3 : b4);
  int yy0 = p >> 6, xx0 = p & 63;
  float acc = bb[q];
  const float* xin = x + ((size_t)b * CCH + q * 4) * LL;
  #pragma unroll
  for (int ky = 0; ky < 3; ky++) {
    int yy = yy0 + (ky - 1) * dil;
    if (yy < 0 || yy >= HWD) continue;
    #pragma unroll
    for (int kx = 0; kx < 3; kx++) {
      int xx = xx0 + (kx - 1) * dil;
      if (xx < 0 || xx >= HWD) continue;
      int pp = (yy << 6) + xx;
      #pragma unroll
      for (int ci = 0; ci < 4; ci++)
        acc += w[ci * 9 + ky * 3 + kx] * xin[(size_t)ci * LL + pp];
    }
  }
  f[idx] = acc;
}

// ---------------- K2: fuse 1x1 (96->96) ----------------
__global__ __launch_bounds__(256) void k_fuse(const float* __restrict__ f,
    const float* __restrict__ fw, const float* __restrict__ fb, float* __restrict__ h) {
  int idx = blockIdx.x * 256 + threadIdx.x;
  int p = idx & (LL - 1);
  int o = (idx >> 12) % CCH;
  int b = idx / (CCH * LL);
  const float* fr = f + (size_t)b * CCH * LL + p;
  const float* wr = fw + o * CCH;
  float acc = fb[o];
  for (int c = 0; c < CCH; c++) acc += wr[c] * fr[(size_t)c * LL];
  h[idx] = acc;
}

// ---------------- K3: depthwise 3x3 (edge) ----------------
__global__ __launch_bounds__(256) void k_edge(const float* __restrict__ h,
    const float* __restrict__ ew, float* __restrict__ edge) {
  int idx = blockIdx.x * 256 + threadIdx.x;
  int p = idx & (LL - 1);
  int c = (idx >> 12) % CCH;
  int b = idx / (CCH * LL);
  int yy0 = p >> 6, xx0 = p & 63;
  const float* w = ew + c * 9;
  const float* hr = h + ((size_t)b * CCH + c) * LL;
  float acc = 0.f;
  #pragma unroll
  for (int ky = 0; ky < 3; ky++) {
    int yy = yy0 + ky - 1;
    if (yy < 0 || yy >= HWD) continue;
    #pragma unroll
    for (int kx = 0; kx < 3; kx++) {
      int xx = xx0 + kx - 1;
      if (xx < 0 || xx >= HWD) continue;
      acc += w[ky * 3 + kx] * hr[(yy << 6) + xx];
    }
  }
  edge[idx] = acc;
}

// ---------------- K4: 1x1 96->24 ----------------
__global__ __launch_bounds__(256) void k_e1(const float* __restrict__ edge,
    const float* __restrict__ w, const float* __restrict__ bias, float* __restrict__ e) {
  int idx = blockIdx.x * 256 + threadIdx.x;         // B*24*L
  int p = idx & (LL - 1);
  int q = (idx >> 12) % QQ;
  int b = idx / (QQ * LL);
  const float* er = edge + (size_t)b * CCH * LL + p;
  const float* wr = w + q * CCH;
  float acc = bias[q];
  for (int c = 0; c < CCH; c++) acc += wr[c] * er[(size_t)c * LL];
  e[idx] = acc;
}

// ---------------- K5: BN stats over (B,H,W) per channel ----------------
__global__ __launch_bounds__(256) void k_bnstats(const float* __restrict__ e,
    const float* __restrict__ g, const float* __restrict__ bb, float* __restrict__ bn) {
  int q = blockIdx.x, tid = threadIdx.x;
  __shared__ float rs[256], r2[256];
  float s = 0.f, s2 = 0.f;
  for (int b = 0; b < 2; b++) {
    const float* er = e + ((size_t)b * QQ + q) * LL;
    for (int p = tid; p < LL; p += 256) { float v = er[p]; s += v; s2 += v * v; }
  }
  rs[tid] = s; r2[tid] = s2; __syncthreads();
  for (int st = 128; st > 0; st >>= 1) {
    if (tid < st) { rs[tid] += rs[tid + st]; r2[tid] += r2[tid + st]; }
    __syncthreads();
  }
  if (tid == 0) {
    float mu = rs[0] / (2.f * LL);
    float var = r2[0] / (2.f * LL) - mu * mu;
    float sc = g[q] * rsqrtf(var + 1e-5f);
    bn[q] = sc;
    bn[QQ + q] = bb[q] - mu * sc;
  }
}

// ---------------- K6: enh 1x1 24->96, sigmoid gate, h *= (1+sig) ----------------
__global__ __launch_bounds__(256) void k_enh(const float* __restrict__ e,
    const float* __restrict__ bn, const float* __restrict__ w2,
    const float* __restrict__ b2, float* __restrict__ h) {
  int idx = blockIdx.x * 256 + threadIdx.x;
  int p = idx & (LL - 1);
  int o = (idx >> 12) % CCH;
  int b = idx / (CCH * LL);
  const float* er = e + (size_t)b * QQ * LL + p;
  const float* wr = w2 + o * QQ;
  float acc = b2[o];
  #pragma unroll
  for (int q = 0; q < QQ; q++) {
    float en = fmaxf(er[(size_t)q * LL] * bn[q] + bn[QQ + q], 0.f);
    acc += wr[q] * en;
  }
  float sig = 1.f / (1.f + __expf(-acc));
  h[idx] *= (1.f + sig);
}

// ---------------- K7a: per-(b,c) mean+max over L ----------------
__global__ __launch_bounds__(256) void k_rowreduce(const float* __restrict__ t, float* __restrict__ sout) {
  int row = blockIdx.x, tid = threadIdx.x;   // row = b*96+c
  __shared__ float rs[256], rm[256];
  float s = 0.f, m = -3.402823466e38f;
  const float* tr = t + (size_t)row * LL;
  for (int p = tid; p < LL; p += 256) { float v = tr[p]; s += v; m = fmaxf(m, v); }
  rs[tid] = s; rm[tid] = m; __syncthreads();
  for (int st = 128; st > 0; st >>= 1) {
    if (tid < st) { rs[tid] += rs[tid + st]; rm[tid] = fmaxf(rm[tid], rm[tid + st]); }
    __syncthreads();
  }
  if (tid == 0) sout[row] = rs[0] / (float)LL + rm[0];
}

// ---------------- K7b: channel-recal tiny FC ----------------
__global__ __launch_bounds__(128) void k_recal_fc(const float* __restrict__ s1,
    const float* __restrict__ fc1, const float* __restrict__ fc2, float* __restrict__ wout) {
  int b = blockIdx.x, tid = threadIdx.x;
  __shared__ float sv[CCH];
  __shared__ float hid[QQ];
  if (tid < CCH) sv[tid] = s1[b * CCH + tid];
  __syncthreads();
  if (tid < QQ) {
    float a = 0.f;
    for (int c = 0; c < CCH; c++) a += sv[c] * fc1[tid * CCH + c];
    hid[tid] = fmaxf(a, 0.f);
  }
  __syncthreads();
  if (tid < CCH) {
    float a = 0.f;
    #pragma unroll
    for (int q = 0; q < QQ; q++) a += hid[q] * fc2[tid * QQ + q];
    wout[b * CCH + tid] = 1.f / (1.f + __expf(-a));
  }
}

// ---------------- K8a: apply recal + LayerNorm(C=96) -> hn (B,L,96) ----------------
__global__ __launch_bounds__(128) void k_recal_ln(const float* __restrict__ h,
    const float* __restrict__ w1buf, const float* __restrict__ ng,
    const float* __restrict__ nb, float* __restrict__ hn) {
  int pb = blockIdx.x;                 // b*L+p
  int b = pb >> 12, p = pb & (LL - 1);
  int tid = threadIdx.x;
  __shared__ float red[128];
  __shared__ float smu, srs;
  float v = 0.f;
  if (tid < CCH) v = h[((size_t)b * CCH + tid) * LL + p] * w1buf[b * CCH + tid];
  red[tid] = v; __syncthreads();
  for (int s = 64; s > 0; s >>= 1) { if (tid < s) red[tid] += red[tid + s]; __syncthreads(); }
  if (tid == 0) smu = red[0] / (float)CCH;
  __syncthreads();
  float xcv = (tid < CCH) ? v - smu : 0.f;
  red[tid] = xcv * xcv; __syncthreads();
  for (int s = 64; s > 0; s >>= 1) { if (tid < s) red[tid] += red[tid + s]; __syncthreads(); }
  if (tid == 0) srs = rsqrtf(red[0] / (float)CCH + 1e-5f);
  __syncthreads();
  if (tid < CCH) hn[((size_t)b * LL + p) * CCH + tid] = xcv * srs * ng[tid] + nb[tid];
}

// ---------------- K8b: in_proj (96 -> 384), split xm/z ----------------
__global__ __launch_bounds__(384) void k_inproj(const float* __restrict__ hn,
    const float* __restrict__ W, float* __restrict__ xm, float* __restrict__ z) {
  int pix0 = blockIdx.x * 16;          // over B*L
  int tid = threadIdx.x;
  __shared__ float a[16][CCH];
  for (int t = tid; t < 16 * CCH; t += 384) a[t / CCH][t % CCH] = hn[(size_t)pix0 * CCH + t];
  __syncthreads();
  const float* wr = W + tid * CCH;
  float acc[16];
  #pragma unroll
  for (int j = 0; j < 16; j++) acc[j] = 0.f;
  for (int c = 0; c < CCH; c += 4) {
    float4 wv = *(const float4*)(wr + c);
    #pragma unroll
    for (int j = 0; j < 16; j++) {
      float4 av = *(const float4*)(&a[j][c]);
      acc[j] = fmaf(av.x, wv.x, fmaf(av.y, wv.y, fmaf(av.z, wv.z, fmaf(av.w, wv.w, acc[j]))));
    }
  }
  float* dst = (tid < DDI) ? xm : z;
  int oo = (tid < DDI) ? tid : tid - DDI;
  #pragma unroll
  for (int j = 0; j < 16; j++) dst[(size_t)(pix0 + j) * DDI + oo] = acc[j];
}

// ---------------- K9: depthwise 3x3 on xm + bias + silu -> xc ----------------
__global__ __launch_bounds__(256) void k_ssconv(const float* __restrict__ xm,
    const float* __restrict__ w, const float* __restrict__ bias, float* __restrict__ xc) {
  int idx = blockIdx.x * 256 + threadIdx.x;      // B*L*192, d fastest
  int d = idx % DDI;
  int p = (idx / DDI) & (LL - 1);
  int b = idx / (DDI * LL);
  int yy0 = p >> 6, xx0 = p & 63;
  float acc = bias[d];
  const float* wr = w + d * 9;
  const float* xr = xm + (size_t)b * LL * DDI + d;
  #pragma unroll
  for (int ky = 0; ky < 3; ky++) {
    int yy = yy0 + ky - 1;
    if (yy < 0 || yy >= HWD) continue;
    #pragma unroll
    for (int kx = 0; kx < 3; kx++) {
      int xx = xx0 + kx - 1;
      if (xx < 0 || xx >= HWD) continue;
      acc += wr[ky * 3 + kx] * xr[(size_t)((yy << 6) + xx) * DDI];
    }
  }
  xc[(size_t)idx] = acc / (1.f + __expf(-acc));
}

// ---------------- K10: x_proj (192->38) + dt proj (6->192) + softplus ----------------
// lanes = positions (weights wave-uniform from LDS), 128 positions/block, 2/thread
__global__ __launch_bounds__(256) void k_xdbl(const float* __restrict__ xc,
    const float* __restrict__ xpw, const float* __restrict__ dtw,
    const float* __restrict__ dtb, float* __restrict__ dts, float* __restrict__ bcb) {
  int lt = blockIdx.x;                 // LL/XT tiles
  int bk = blockIdx.y;                 // b*4+k
  int b = bk >> 2, k = bk & 3;
  int t = threadIdx.x;
  __shared__ float xs[XT][196];        // pad 4 -> 16B-aligned b128, min-conflict
  __shared__ float wbuf[38 * 192];     // k-specific x_proj weights; reused as dtr
  int l0 = lt * XT;
  // stage weights (coalesced, once per block)
  {
    const float4* src = (const float4*)(xpw + (size_t)k * 38 * DDI);
    float4* dst = (float4*)wbuf;
    for (int i = t; i < 38 * DDI / 4; i += 256) dst[i] = src[i];
  }
  // stage x tile (contiguous 768B rows regardless of direction k)
  for (int i = t; i < XT * 48; i += 256) {
    int li = i / 48, dq = i % 48;
    int p = map_k(k, l0 + li);
    float4 v = *(const float4*)(xc + ((size_t)b * LL + p) * DDI + dq * 4);
    *(float4*)(&xs[li][dq * 4]) = v;
  }
  __syncthreads();
  int li = t & 63, cg = t >> 6;        // wave-uniform cg
  float acc0[10], acc1[10];
  #pragma unroll
  for (int j = 0; j < 10; j++) { acc0[j] = 0.f; acc1[j] = 0.f; }
  for (int dq = 0; dq < 48; dq++) {
    float4 x0 = *(const float4*)(&xs[li][dq * 4]);
    float4 x1 = *(const float4*)(&xs[li + 64][dq * 4]);
    #pragma unroll
    for (int j = 0; j < 10; j++) {
      int c = cg + 4 * j;
      if (c < 38) {
        float4 wv = *(const float4*)(&wbuf[c * DDI + dq * 4]);   // uniform broadcast
        acc0[j] = fmaf(x0.x, wv.x, fmaf(x0.y, wv.y, fmaf(x0.z, wv.z, fmaf(x0.w, wv.w, acc0[j]))));
        acc1[j] = fmaf(x1.x, wv.x, fmaf(x1.y, wv.y, fmaf(x1.z, wv.z, fmaf(x1.w, wv.w, acc1[j]))));
      }
    }
  }
  // B/C outputs
  #pragma unroll
  for (int j = 0; j < 10; j++) {
    int c = cg + 4 * j;
    if (c >= 6 && c < 38) {
      bcb[((size_t)bk * LL + l0 + li) * 32 + (c - 6)] = acc0[j];
      bcb[((size_t)bk * LL + l0 + li + 64) * 32 + (c - 6)] = acc1[j];
    }
  }
  __syncthreads();                      // all wbuf reads done
  float* dtr = wbuf;                    // [XT][6]
  #pragma unroll
  for (int j = 0; j < 2; j++) {
    int c = cg + 4 * j;
    if (c < 6) {
      dtr[li * 6 + c] = acc0[j];
      dtr[(li + 64) * 6 + c] = acc1[j];
    }
  }
  __syncthreads();
  // phase 2: dt projection (6 -> 192) + softplus
  for (int i = t; i < XT * DDI; i += 256) {
    int lp = i / DDI, dd = i % DDI;
    const float* wr = dtw + (size_t)(k * DDI + dd) * 6;
    const float* dr = dtr + lp * 6;
    float a = dtb[k * DDI + dd];
    #pragma unroll
    for (int r = 0; r < 6; r++) a = fmaf(wr[r], dr[r], a);
    float sp = (a > 15.f) ? a : __logf(1.f + __expf(a));
    dts[((size_t)bk * LL + l0 + lp) * DDI + dd] = sp;
  }
}

// ---------------- K11: chunked selective scan ----------------
template <int PASS>
__global__ __launch_bounds__(192) void k_scan(const float* __restrict__ dts,
    const float* __restrict__ bcb, const float* __restrict__ xc,
    const float* __restrict__ A_logs, float* __restrict__ hl, float* __restrict__ sd,
    const float* __restrict__ hin, float* __restrict__ yk) {
  int ch = blockIdx.x, bk = blockIdx.y;
  int b = bk >> 2, k = bk & 3;
  int d = threadIdx.x;
  float Av[NST];
  #pragma unroll
  for (int n = 0; n < NST; n++) Av[n] = -__expf(A_logs[(size_t)(k * DDI + d) * NST + n]);
  bool pw = true;
  #pragma unroll
  for (int n = 1; n < NST; n++) pw = pw && (fabsf(Av[n] - (float)(n + 1) * Av[0]) <= 1e-3f * (n + 1));
  float h[NST];
  if (PASS == 0) {
    #pragma unroll
    for (int n = 0; n < NST; n++) h[n] = 0.f;
  } else {
    const float* hp = hin + ((size_t)(bk * DDI + d) * NCH + ch) * NST;
    #pragma unroll
    for (int n = 0; n < NST; n++) h[n] = hp[n];
  }
  float sumdt = 0.f;
  __shared__ float bcs[TSC][32];
  int l0 = ch * CLEN;
  for (int t0 = 0; t0 < CLEN; t0 += TSC) {
    __syncthreads();
    for (int t = d; t < TSC * 32; t += 192)
      bcs[t >> 5][t & 31] = bcb[((size_t)bk * LL + l0 + t0 + (t >> 5)) * 32 + (t & 31)];
    __syncthreads();
    for (int tt = 0; tt < TSC; tt++) {
      int l = l0 + t0 + tt;
      float dt = dts[((size_t)bk * LL + l) * DDI + d];
      int p = map_k(k, l);
      float u = xc[((size_t)b * LL + p) * DDI + d];
      float dtu = dt * u;
      if (PASS == 0) sumdt += dt;
      float eA[NST];
      if (pw) {
        float E = __expf(dt * Av[0]);
        float en = 1.f;
        #pragma unroll
        for (int n = 0; n < NST; n++) { en *= E; eA[n] = en; }
      } else {
        #pragma unroll
        for (int n = 0; n < NST; n++) eA[n] = __expf(dt * Av[n]);
      }
      float y = 0.f;
      #pragma unroll
      for (int n = 0; n < NST; n++) {
        h[n] = eA[n] * h[n] + dtu * bcs[tt][n];
        y += h[n] * bcs[tt][16 + n];
      }
      if (PASS == 1) yk[((size_t)bk * LL + p) * DDI + d] = y;
    }
  }
  if (PASS == 0) {
    float* hp = hl + ((size_t)(bk * DDI + d) * NCH + ch) * NST;
    #pragma unroll
    for (int n = 0; n < NST; n++) hp[n] = h[n];
    sd[(size_t)(bk * DDI + d) * NCH + ch] = sumdt;
  }
}

// ---------------- K11b: chunk-carry propagation ----------------
__global__ __launch_bounds__(256) void k_carry(const float* __restrict__ A_logs,
    const float* __restrict__ hl, const float* __restrict__ sd, float* __restrict__ hin) {
  int idx = blockIdx.x * 256 + threadIdx.x;  // 8*192*16
  int n = idx & 15;
  int d = (idx >> 4) % DDI;
  int bk = idx / (DDI * NST);
  int k = bk & 3;
  float Aval = -__expf(A_logs[(size_t)(k * DDI + d) * NST + n]);
  float h = 0.f;
  size_t base = (size_t)(bk * DDI + d) * NCH;
  for (int ch = 0; ch < NCH; ch++) {
    hin[(base + ch) * NST + n] = h;
    h = __expf(Aval * sd[base + ch]) * h + hl[(base + ch) * NST + n];
  }
}

// ---------------- K12a: combine 4 dirs + D*u + LN(192) + silu(z) -> g ----------------
__global__ __launch_bounds__(192) void k_combine(const float* __restrict__ yk,
    const float* __restrict__ xc, const float* __restrict__ Ds, const float* __restrict__ z,
    const float* __restrict__ ong, const float* __restrict__ onb, float* __restrict__ g) {
  int pb = blockIdx.x;
  int b = pb >> 12, p = pb & (LL - 1);
  int d = threadIdx.x;
  __shared__ float red[DDI];
  __shared__ float smu, srs;
  size_t base = ((size_t)b * 4 * LL + p) * DDI + d;
  float v = yk[base] + yk[base + (size_t)LL * DDI] + yk[base + 2ul * LL * DDI] + yk[base + 3ul * LL * DDI];
  v += (Ds[d] + Ds[DDI + d] + Ds[2 * DDI + d] + Ds[3 * DDI + d]) * xc[((size_t)b * LL + p) * DDI + d];
  red[d] = v; __syncthreads();
  if (d < 64) red[d] += red[d + 128];
  __syncthreads();
  for (int s = 64; s > 0; s >>= 1) { if (d < s) red[d] += red[d + s]; __syncthreads(); }
  if (d == 0) smu = red[0] / (float)DDI;
  __syncthreads();
  float xcv = v - smu;
  red[d] = xcv * xcv; __syncthreads();
  if (d < 64) red[d] += red[d + 128];
  __syncthreads();
  for (int s = 64; s > 0; s >>= 1) { if (d < s) red[d] += red[d + s]; __syncthreads(); }
  if (d == 0) srs = rsqrtf(red[0] / (float)DDI + 1e-5f);
  __syncthreads();
  float yv = xcv * srs * ong[d] + onb[d];
  float zz = z[((size_t)b * LL + p) * DDI + d];
  g[((size_t)b * LL + p) * DDI + d] = yv * (zz / (1.f + __expf(-zz)));
}

// ---------------- K12b: out_proj (192 -> 96) -> y2 (B,96,L) ----------------
__global__ __launch_bounds__(192) void k_outproj(const float* __restrict__ g,
    const float* __restrict__ W, float* __restrict__ y2) {
  int pix0 = blockIdx.x * 32;          // over B*L
  int b = pix0 / LL, p0 = pix0 & (LL - 1);
  int tid = threadIdx.x;
  __shared__ float a[32][DDI];
  for (int t = tid; t < 32 * DDI; t += 192) a[t / DDI][t % DDI] = g[(size_t)pix0 * DDI + t];
  __syncthreads();
  int o = tid % CCH, ph = tid / CCH;
  const float* wr = W + o * DDI;
  float acc[16];
  #pragma unroll
  for (int j = 0; j < 16; j++) acc[j] = 0.f;
  for (int c = 0; c < DDI; c += 4) {
    float4 wv = *(const float4*)(wr + c);
    #pragma unroll
    for (int j = 0; j < 16; j++) {
      float4 av = *(const float4*)(&a[ph * 16 + j][c]);
      acc[j] = fmaf(av.x, wv.x, fmaf(av.y, wv.y, fmaf(av.z, wv.z, fmaf(av.w, wv.w, acc[j]))));
    }
  }
  float* base = y2 + ((size_t)b * CCH + o) * LL + p0 + ph * 16;
  #pragma unroll
  for (int jj = 0; jj < 4; jj++)
    *(float4*)(base + jj * 4) = make_float4(acc[jj * 4], acc[jj * 4 + 1], acc[jj * 4 + 2], acc[jj * 4 + 3]);
}

// ---------------- K14: recal-apply + proj 1x1 + residual ----------------
__global__ __launch_bounds__(256) void k_final(const float* __restrict__ x,
    const float* __restrict__ y2, const float* __restrict__ w2buf,
    const float* __restrict__ pw, const float* __restrict__ pb, float* __restrict__ out) {
  int idx = blockIdx.x * 256 + threadIdx.x;
  int p = idx & (LL - 1);
  int c = (idx >> 12) % CCH;
  int b = idx / (CCH * LL);
  const float* yr = y2 + (size_t)b * CCH * LL + p;
  const float* wr = pw + c * CCH;
  const float* wc = w2buf + b * CCH;
  float acc = pb[c];
  for (int o = 0; o < CCH; o++) acc += wr[o] * yr[(size_t)o * LL] * wc[o];
  out[idx] = x[idx] + acc;
}

extern "C" void kernel_launch(void* const* d_in, const int* in_sizes, int n_in,
                              void* d_out, int out_size, void* d_ws, size_t ws_size,
                              hipStream_t stream) {
  const float* x        = (const float*)d_in[0];
  const float* arf_w1   = (const float*)d_in[1];
  const float* arf_b1   = (const float*)d_in[2];
  const float* arf_w2   = (const float*)d_in[3];
  const float* arf_b2   = (const float*)d_in[4];
  const float* arf_w3   = (const float*)d_in[5];
  const float* arf_b3   = (const float*)d_in[6];
  const float* arf_w4   = (const float*)d_in[7];
  const float* arf_b4   = (const float*)d_in[8];
  const float* fuse_w   = (const float*)d_in[9];
  const float* fuse_b   = (const float*)d_in[10];
  const float* edge_w   = (const float*)d_in[11];
  const float* enh_w1   = (const float*)d_in[12];
  const float* enh_b1   = (const float*)d_in[13];
  const float* bn_g     = (const float*)d_in[14];
  const float* bn_b     = (const float*)d_in[15];
  const float* enh_w2   = (const float*)d_in[16];
  const float* enh_b2   = (const float*)d_in[17];
  const float* pre_fc1  = (const float*)d_in[18];
  const float* pre_fc2  = (const float*)d_in[19];
  const float* norm_g   = (const float*)d_in[20];
  const float* norm_b   = (const float*)d_in[21];
  const float* in_proj_w= (const float*)d_in[22];
  const float* ss_conv_w= (const float*)d_in[23];
  const float* ss_conv_b= (const float*)d_in[24];
  const float* x_proj_w = (const float*)d_in[25];
  const float* dt_w     = (const float*)d_in[26];
  const float* dt_b     = (const float*)d_in[27];
  const float* A_logs   = (const float*)d_in[28];
  const float* Ds       = (const float*)d_in[29];
  const float* out_ng   = (const float*)d_in[30];
  const float* out_nb   = (const float*)d_in[31];
  const float* out_proj_w = (const float*)d_in[32];
  const float* post_fc1 = (const float*)d_in[33];
  const float* post_fc2 = (const float*)d_in[34];
  const float* proj_w   = (const float*)d_in[35];
  const float* proj_b   = (const float*)d_in[36];

  float* ws = (float*)d_ws;
  float* fbuf  = ws + OFF_F;
  float* hbuf  = ws + OFF_H;
  float* ebuf  = ws + OFF_E;
  float* bnbuf = ws + OFF_BN;
  float* s1buf = ws + OFF_S1;
  float* w1buf = ws + OFF_W1;
  float* s2buf = ws + OFF_S2;
  float* w2buf = ws + OFF_W2;
  float* hnbuf = ws + OFF_HN;
  float* xmbuf = ws + OFF_XM;
  float* zbuf  = ws + OFF_Z;
  float* xcbuf = ws + OFF_XC;
  float* dtsbuf= ws + OFF_DTS;
  float* bcbuf = ws + OFF_BC;
  float* ykbuf = ws + OFF_YK;
  float* hlbuf = ws + OFF_HL;
  float* sdbuf = ws + OFF_SD;
  float* hinbuf= ws + OFF_HIN;
  float* y2buf = ws + OFF_Y2;
  float* gbuf  = xmbuf;   // reuse (xm dead after k_ssconv)

  k_arf<<<3072, 256, 0, stream>>>(x, arf_w1, arf_b1, arf_w2, arf_b2, arf_w3, arf_b3, arf_w4, arf_b4, fbuf);
  k_fuse<<<3072, 256, 0, stream>>>(fbuf, fuse_w, fuse_b, hbuf);
  k_edge<<<3072, 256, 0, stream>>>(hbuf, edge_w, fbuf);   // edge reuses fbuf
  k_e1<<<768, 256, 0, stream>>>(fbuf, enh_w1, enh_b1, ebuf);
  k_bnstats<<<24, 256, 0, stream>>>(ebuf, bn_g, bn_b, bnbuf);
  k_enh<<<3072, 256, 0, stream>>>(ebuf, bnbuf, enh_w2, enh_b2, hbuf);
  k_rowreduce<<<192, 256, 0, stream>>>(hbuf, s1buf);
  k_recal_fc<<<2, 128, 0, stream>>>(s1buf, pre_fc1, pre_fc2, w1buf);
  k_recal_ln<<<8192, 128, 0, stream>>>(hbuf, w1buf, norm_g, norm_b, hnbuf);
  k_inproj<<<512, 384, 0, stream>>>(hnbuf, in_proj_w, xmbuf, zbuf);
  k_ssconv<<<6144, 256, 0, stream>>>(xmbuf, ss_conv_w, ss_conv_b, xcbuf);
  k_xdbl<<<dim3(LL / XT, 8), 256, 0, stream>>>(xcbuf, x_proj_w, dt_w, dt_b, dtsbuf, bcbuf);
  k_scan<0><<<dim3(NCH, 8), 192, 0, stream>>>(dtsbuf, bcbuf, xcbuf, A_logs, hlbuf, sdbuf, nullptr, nullptr);
  k_carry<<<96, 256, 0, stream>>>(A_logs, hlbuf, sdbuf, hinbuf);
  k_scan<1><<<dim3(NCH, 8), 192, 0, stream>>>(dtsbuf, bcbuf, xcbuf, A_logs, nullptr, nullptr, hinbuf, ykbuf);
  k_combine<<<8192, 192, 0, stream>>>(ykbuf, xcbuf, Ds, zbuf, out_ng, out_nb, gbuf);
  k_outproj<<<256, 192, 0, stream>>>(gbuf, out_proj_w, y2buf);
  k_rowreduce<<<192, 256, 0, stream>>>(y2buf, s2buf);
  k_recal_fc<<<2, 128, 0, stream>>>(s2buf, post_fc1, post_fc2, w2buf);
  k_final<<<3072, 256, 0, stream>>>(x, y2buf, w2buf, proj_w, proj_b, (float*)d_out);
  (void)in_sizes; (void)n_in; (void)out_size; (void)ws_size;
}

// Round 3
// 312.544 us; speedup vs baseline: 1.4248x; 1.2219x over previous
//
#include <hip/hip_runtime.h>
#include <cmath>

#define LL   4096
#define HWD  64
#define CCH  96
#define QQ   24
#define DDI  192
#define NST  16
#define NCH  64      // chunks in scan
#define CLEN 64      // steps per chunk
#define TSC  32      // steps staged per LDS tile
#define XT   128     // positions per block in k_xdbl

// ---------------- workspace layout (floats) ----------------
static const size_t OFF_F   = 0;          // 786432  f (concat arf) -> reused as edge, then hl
static const size_t OFF_H   = 786432;     // 786432  h               -> hl (upper half)
static const size_t OFF_E   = 1572864;    // 196608  e (raw)         -> sd
static const size_t OFF_BN  = 1769472;    // 64      bn scale[24], shift[24]
static const size_t OFF_S1  = 1769536;    // 192
static const size_t OFF_W1  = 1769728;    // 192
static const size_t OFF_S2  = 1769920;    // 192
static const size_t OFF_W2  = 1770112;    // 192
static const size_t OFF_HN  = 1770304;    // 786432  hn (B,L,96)
static const size_t OFF_XM  = 2556736;    // 1572864 xm (B,L,192) -> hin -> g
static const size_t OFF_Z   = 4129600;    // 1572864 z  (B,L,192)
static const size_t OFF_XC  = 5702464;    // 1572864 xc (B,L,192)
static const size_t OFF_DTS = 7275328;    // 6291456 dts (B,K,L,192)
static const size_t OFF_BC  = 13566784;   // 1048576 B|C (B,K,L,32)
static const size_t OFF_YK  = 14615360;   // 6291456 yk (B,K,L,192) at hw position
static const size_t OFF_Y2  = 22528832;   // 786432  y2 (B,96,L)
// aliases (regions dead by scan time):
static const size_t OFF_HL  = OFF_F;      // 8*192*64*16 = 1572864
static const size_t OFF_SD  = OFF_E;      // 8*192*64   = 98304
static const size_t OFF_HIN = OFF_XM;     // 1572864 (g reuses same region after pass 1)

static __device__ __forceinline__ int map_k(int k, int l) {
  int ll = (k & 2) ? (LL - 1 - l) : l;
  return (k & 1) ? (((ll & 63) << 6) | (ll >> 6)) : ll;
}

// ---------------- K1: ARF grouped dilated convs (concat f1..f4) ----------------
__global__ __launch_bounds__(256) void k_arf(const float* __restrict__ x,
    const float* __restrict__ w1, const float* __restrict__ b1,
    const float* __restrict__ w2, const float* __restrict__ b2,
    const float* __restrict__ w3, const float* __restrict__ b3,
    const float* __restrict__ w4, const float* __restrict__ b4,
    float* __restrict__ f) {
  int idx = blockIdx.x * 256 + threadIdx.x;            // B*96*L
  int p = idx & (LL - 1);
  int oc = (idx >> 12) % CCH;
  int b  = idx / (CCH * LL);
  int i = oc / QQ, q = oc % QQ;
  int dil = 1 << i;
  const float* w  = (i == 0 ? w1 : i == 1 ? w2 : i == 2 ? w3 : w4) + q * 36;
  const float* bb = (i == 0 ? b1 : i == 1 ? b2 : i == 2 ? b3 : b4);
  int yy0 = p >> 6, xx0 = p & 63;
  float acc = bb[q];
  const float* xin = x + ((size_t)b * CCH + q * 4) * LL;
  #pragma unroll
  for (int ky = 0; ky < 3; ky++) {
    int yy = yy0 + (ky - 1) * dil;
    if (yy < 0 || yy >= HWD) continue;
    #pragma unroll
    for (int kx = 0; kx < 3; kx++) {
      int xx = xx0 + (kx - 1) * dil;
      if (xx < 0 || xx >= HWD) continue;
      int pp = (yy << 6) + xx;
      #pragma unroll
      for (int ci = 0; ci < 4; ci++)
        acc += w[ci * 9 + ky * 3 + kx] * xin[(size_t)ci * LL + pp];
    }
  }
  f[idx] = acc;
}

// ---------------- K2: fuse 1x1 (96->96) ----------------
__global__ __launch_bounds__(256) void k_fuse(const float* __restrict__ f,
    const float* __restrict__ fw, const float* __restrict__ fb, float* __restrict__ h) {
  int idx = blockIdx.x * 256 + threadIdx.x;
  int p = idx & (LL - 1);
  int o = (idx >> 12) % CCH;
  int b = idx / (CCH * LL);
  const float* fr = f + (size_t)b * CCH * LL + p;
  const float* wr = fw + o * CCH;
  float acc = fb[o];
  for (int c = 0; c < CCH; c++) acc += wr[c] * fr[(size_t)c * LL];
  h[idx] = acc;
}

// ---------------- K3: depthwise 3x3 (edge) ----------------
__global__ __launch_bounds__(256) void k_edge(const float* __restrict__ h,
    const float* __restrict__ ew, float* __restrict__ edge) {
  int idx = blockIdx.x * 256 + threadIdx.x;
  int p = idx & (LL - 1);
  int c = (idx >> 12) % CCH;
  int b = idx / (CCH * LL);
  int yy0 = p >> 6, xx0 = p & 63;
  const float* w = ew + c * 9;
  const float* hr = h + ((size_t)b * CCH + c) * LL;
  float acc = 0.f;
  #pragma unroll
  for (int ky = 0; ky < 3; ky++) {
    int yy = yy0 + ky - 1;
    if (yy < 0 || yy >= HWD) continue;
    #pragma unroll
    for (int kx = 0; kx < 3; kx++) {
      int xx = xx0 + kx - 1;
      if (xx < 0 || xx >= HWD) continue;
      acc += w[ky * 3 + kx] * hr[(yy << 6) + xx];
    }
  }
  edge[idx] = acc;
}

// ---------------- K4: 1x1 96->24 ----------------
__global__ __launch_bounds__(256) void k_e1(const float* __restrict__ edge,
    const float* __restrict__ w, const float* __restrict__ bias, float* __restrict__ e) {
  int idx = blockIdx.x * 256 + threadIdx.x;         // B*24*L
  int p = idx & (LL - 1);
  int q = (idx >> 12) % QQ;
  int b = idx / (QQ * LL);
  const float* er = edge + (size_t)b * CCH * LL + p;
  const float* wr = w + q * CCH;
  float acc = bias[q];
  for (int c = 0; c < CCH; c++) acc += wr[c] * er[(size_t)c * LL];
  e[idx] = acc;
}

// ---------------- K5: BN stats over (B,H,W) per channel ----------------
__global__ __launch_bounds__(256) void k_bnstats(const float* __restrict__ e,
    const float* __restrict__ g, const float* __restrict__ bb, float* __restrict__ bn) {
  int q = blockIdx.x, tid = threadIdx.x;
  __shared__ float rs[256], r2[256];
  float s = 0.f, s2 = 0.f;
  for (int b = 0; b < 2; b++) {
    const float* er = e + ((size_t)b * QQ + q) * LL;
    for (int p = tid; p < LL; p += 256) { float v = er[p]; s += v; s2 += v * v; }
  }
  rs[tid] = s; r2[tid] = s2; __syncthreads();
  for (int st = 128; st > 0; st >>= 1) {
    if (tid < st) { rs[tid] += rs[tid + st]; r2[tid] += r2[tid + st]; }
    __syncthreads();
  }
  if (tid == 0) {
    float mu = rs[0] / (2.f * LL);
    float var = r2[0] / (2.f * LL) - mu * mu;
    float sc = g[q] * rsqrtf(var + 1e-5f);
    bn[q] = sc;
    bn[QQ + q] = bb[q] - mu * sc;
  }
}

// ---------------- K6: enh 1x1 24->96, sigmoid gate, h *= (1+sig) ----------------
__global__ __launch_bounds__(256) void k_enh(const float* __restrict__ e,
    const float* __restrict__ bn, const float* __restrict__ w2,
    const float* __restrict__ b2, float* __restrict__ h) {
  int idx = blockIdx.x * 256 + threadIdx.x;
  int p = idx & (LL - 1);
  int o = (idx >> 12) % CCH;
  int b = idx / (CCH * LL);
  const float* er = e + (size_t)b * QQ * LL + p;
  const float* wr = w2 + o * QQ;
  float acc = b2[o];
  #pragma unroll
  for (int q = 0; q < QQ; q++) {
    float en = fmaxf(er[(size_t)q * LL] * bn[q] + bn[QQ + q], 0.f);
    acc += wr[q] * en;
  }
  float sig = 1.f / (1.f + __expf(-acc));
  h[idx] *= (1.f + sig);
}

// ---------------- K7a: per-(b,c) mean+max over L ----------------
__global__ __launch_bounds__(256) void k_rowreduce(const float* __restrict__ t, float* __restrict__ sout) {
  int row = blockIdx.x, tid = threadIdx.x;   // row = b*96+c
  __shared__ float rs[256], rm[256];
  float s = 0.f, m = -3.402823466e38f;
  const float* tr = t + (size_t)row * LL;
  for (int p = tid; p < LL; p += 256) { float v = tr[p]; s += v; m = fmaxf(m, v); }
  rs[tid] = s; rm[tid] = m; __syncthreads();
  for (int st = 128; st > 0; st >>= 1) {
    if (tid < st) { rs[tid] += rs[tid + st]; rm[tid] = fmaxf(rm[tid], rm[tid + st]); }
    __syncthreads();
  }
  if (tid == 0) sout[row] = rs[0] / (float)LL + rm[0];
}

// ---------------- K7b: channel-recal tiny FC ----------------
__global__ __launch_bounds__(128) void k_recal_fc(const float* __restrict__ s1,
    const float* __restrict__ fc1, const float* __restrict__ fc2, float* __restrict__ wout) {
  int b = blockIdx.x, tid = threadIdx.x;
  __shared__ float sv[CCH];
  __shared__ float hid[QQ];
  if (tid < CCH) sv[tid] = s1[b * CCH + tid];
  __syncthreads();
  if (tid < QQ) {
    float a = 0.f;
    for (int c = 0; c < CCH; c++) a += sv[c] * fc1[tid * CCH + c];
    hid[tid] = fmaxf(a, 0.f);
  }
  __syncthreads();
  if (tid < CCH) {
    float a = 0.f;
    #pragma unroll
    for (int q = 0; q < QQ; q++) a += hid[q] * fc2[tid * QQ + q];
    wout[b * CCH + tid] = 1.f / (1.f + __expf(-a));
  }
}

// ---------------- K8a: apply recal + LayerNorm(C=96) -> hn (B,L,96) ----------------
__global__ __launch_bounds__(128) void k_recal_ln(const float* __restrict__ h,
    const float* __restrict__ w1buf, const float* __restrict__ ng,
    const float* __restrict__ nb, float* __restrict__ hn) {
  int pb = blockIdx.x;                 // b*L+p
  int b = pb >> 12, p = pb & (LL - 1);
  int tid = threadIdx.x;
  __shared__ float red[128];
  __shared__ float smu, srs;
  float v = 0.f;
  if (tid < CCH) v = h[((size_t)b * CCH + tid) * LL + p] * w1buf[b * CCH + tid];
  red[tid] = v; __syncthreads();
  for (int s = 64; s > 0; s >>= 1) { if (tid < s) red[tid] += red[tid + s]; __syncthreads(); }
  if (tid == 0) smu = red[0] / (float)CCH;
  __syncthreads();
  float xcv = (tid < CCH) ? v - smu : 0.f;
  red[tid] = xcv * xcv; __syncthreads();
  for (int s = 64; s > 0; s >>= 1) { if (tid < s) red[tid] += red[tid + s]; __syncthreads(); }
  if (tid == 0) srs = rsqrtf(red[0] / (float)CCH + 1e-5f);
  __syncthreads();
  if (tid < CCH) hn[((size_t)b * LL + p) * CCH + tid] = xcv * srs * ng[tid] + nb[tid];
}

// ---------------- K8b: in_proj (96 -> 384), split xm/z ----------------
__global__ __launch_bounds__(384) void k_inproj(const float* __restrict__ hn,
    const float* __restrict__ W, float* __restrict__ xm, float* __restrict__ z) {
  int pix0 = blockIdx.x * 16;          // over B*L
  int tid = threadIdx.x;
  __shared__ float a[16][CCH];
  for (int t = tid; t < 16 * CCH; t += 384) a[t / CCH][t % CCH] = hn[(size_t)pix0 * CCH + t];
  __syncthreads();
  const float* wr = W + tid * CCH;
  float acc[16];
  #pragma unroll
  for (int j = 0; j < 16; j++) acc[j] = 0.f;
  for (int c = 0; c < CCH; c += 4) {
    float4 wv = *(const float4*)(wr + c);
    #pragma unroll
    for (int j = 0; j < 16; j++) {
      float4 av = *(const float4*)(&a[j][c]);
      acc[j] = fmaf(av.x, wv.x, fmaf(av.y, wv.y, fmaf(av.z, wv.z, fmaf(av.w, wv.w, acc[j]))));
    }
  }
  float* dst = (tid < DDI) ? xm : z;
  int oo = (tid < DDI) ? tid : tid - DDI;
  #pragma unroll
  for (int j = 0; j < 16; j++) dst[(size_t)(pix0 + j) * DDI + oo] = acc[j];
}

// ---------------- K9: depthwise 3x3 on xm + bias + silu -> xc ----------------
__global__ __launch_bounds__(256) void k_ssconv(const float* __restrict__ xm,
    const float* __restrict__ w, const float* __restrict__ bias, float* __restrict__ xc) {
  int idx = blockIdx.x * 256 + threadIdx.x;      // B*L*192, d fastest
  int d = idx % DDI;
  int p = (idx / DDI) & (LL - 1);
  int b = idx / (DDI * LL);
  int yy0 = p >> 6, xx0 = p & 63;
  float acc = bias[d];
  const float* wr = w + d * 9;
  const float* xr = xm + (size_t)b * LL * DDI + d;
  #pragma unroll
  for (int ky = 0; ky < 3; ky++) {
    int yy = yy0 + ky - 1;
    if (yy < 0 || yy >= HWD) continue;
    #pragma unroll
    for (int kx = 0; kx < 3; kx++) {
      int xx = xx0 + kx - 1;
      if (xx < 0 || xx >= HWD) continue;
      acc += wr[ky * 3 + kx] * xr[(size_t)((yy << 6) + xx) * DDI];
    }
  }
  xc[(size_t)idx] = acc / (1.f + __expf(-acc));
}

// ---------------- K10: x_proj (192->38) + dt proj (6->192) + softplus ----------------
__global__ __launch_bounds__(256) void k_xdbl(const float* __restrict__ xc,
    const float* __restrict__ xpw, const float* __restrict__ dtw,
    const float* __restrict__ dtb, float* __restrict__ dts, float* __restrict__ bcb) {
  int lt = blockIdx.x;                 // LL/XT tiles
  int bk = blockIdx.y;                 // b*4+k
  int b = bk >> 2, k = bk & 3;
  int t = threadIdx.x;
  __shared__ float xs[XT][196];        // pad 4 -> 16B-aligned b128, min-conflict
  __shared__ float wbuf[38 * 192];     // k-specific x_proj weights; reused as dtr
  int l0 = lt * XT;
  {
    const float4* src = (const float4*)(xpw + (size_t)k * 38 * DDI);
    float4* dst = (float4*)wbuf;
    for (int i = t; i < 38 * DDI / 4; i += 256) dst[i] = src[i];
  }
  for (int i = t; i < XT * 48; i += 256) {
    int li = i / 48, dq = i % 48;
    int p = map_k(k, l0 + li);
    float4 v = *(const float4*)(xc + ((size_t)b * LL + p) * DDI + dq * 4);
    *(float4*)(&xs[li][dq * 4]) = v;
  }
  __syncthreads();
  int li = t & 63, cg = t >> 6;        // wave-uniform cg
  float acc0[10], acc1[10];
  #pragma unroll
  for (int j = 0; j < 10; j++) { acc0[j] = 0.f; acc1[j] = 0.f; }
  for (int dq = 0; dq < 48; dq++) {
    float4 x0 = *(const float4*)(&xs[li][dq * 4]);
    float4 x1 = *(const float4*)(&xs[li + 64][dq * 4]);
    #pragma unroll
    for (int j = 0; j < 10; j++) {
      int c = cg + 4 * j;
      if (c < 38) {
        float4 wv = *(const float4*)(&wbuf[c * DDI + dq * 4]);   // uniform broadcast
        acc0[j] = fmaf(x0.x, wv.x, fmaf(x0.y, wv.y, fmaf(x0.z, wv.z, fmaf(x0.w, wv.w, acc0[j]))));
        acc1[j] = fmaf(x1.x, wv.x, fmaf(x1.y, wv.y, fmaf(x1.z, wv.z, fmaf(x1.w, wv.w, acc1[j]))));
      }
    }
  }
  #pragma unroll
  for (int j = 0; j < 10; j++) {
    int c = cg + 4 * j;
    if (c >= 6 && c < 38) {
      bcb[((size_t)bk * LL + l0 + li) * 32 + (c - 6)] = acc0[j];
      bcb[((size_t)bk * LL + l0 + li + 64) * 32 + (c - 6)] = acc1[j];
    }
  }
  __syncthreads();                      // all wbuf reads done
  float* dtr = wbuf;                    // [XT][6]
  #pragma unroll
  for (int j = 0; j < 2; j++) {
    int c = cg + 4 * j;
    if (c < 6) {
      dtr[li * 6 + c] = acc0[j];
      dtr[(li + 64) * 6 + c] = acc1[j];
    }
  }
  __syncthreads();
  for (int i = t; i < XT * DDI; i += 256) {
    int lp = i / DDI, dd = i % DDI;
    const float* wr = dtw + (size_t)(k * DDI + dd) * 6;
    const float* dr = dtr + lp * 6;
    float a = dtb[k * DDI + dd];
    #pragma unroll
    for (int r = 0; r < 6; r++) a = fmaf(wr[r], dr[r], a);
    float sp = (a > 15.f) ? a : __logf(1.f + __expf(a));
    dts[((size_t)bk * LL + l0 + lp) * DDI + dd] = sp;
  }
}

// ---------------- K11: chunked selective scan (LDS-staged tiles) ----------------
template <int PASS>
__global__ __launch_bounds__(192) void k_scan(const float* __restrict__ dts,
    const float* __restrict__ bcb, const float* __restrict__ xc,
    const float* __restrict__ A_logs, float* __restrict__ hl, float* __restrict__ sd,
    const float* __restrict__ hin, float* __restrict__ yk) {
  int ch = blockIdx.x, bk = blockIdx.y;
  int b = bk >> 2, k = bk & 3;
  int d = threadIdx.x;
  __shared__ float dt_s[TSC][DDI];     // 24 KB
  __shared__ float u_s[TSC][DDI];      // 24 KB
  __shared__ float bcs[TSC][32];       // 4 KB
  float Av[NST];
  #pragma unroll
  for (int n = 0; n < NST; n++) Av[n] = -__expf(A_logs[(size_t)(k * DDI + d) * NST + n]);
  bool pw = true;
  #pragma unroll
  for (int n = 1; n < NST; n++) pw = pw && (fabsf(Av[n] - (float)(n + 1) * Av[0]) <= 1e-3f * (n + 1));
  float h[NST];
  if (PASS == 0) {
    #pragma unroll
    for (int n = 0; n < NST; n++) h[n] = 0.f;
  } else {
    const float* hp = hin + ((size_t)(bk * DDI + d) * NCH + ch) * NST;
    #pragma unroll
    for (int n = 0; n < NST; n++) h[n] = hp[n];
  }
  float sumdt = 0.f;
  int l0 = ch * CLEN;
  for (int t0 = 0; t0 < CLEN; t0 += TSC) {
    __syncthreads();
    // stage dt tile (contiguous)
    {
      const float4* src = (const float4*)(dts + ((size_t)bk * LL + l0 + t0) * DDI);
      float4* dst = (float4*)dt_s;
      for (int i = d; i < TSC * DDI / 4; i += 192) dst[i] = src[i];
    }
    // stage u tile (row-wise; rows contiguous 768B regardless of direction)
    for (int i = d; i < TSC * (DDI / 4); i += 192) {
      int row = i / (DDI / 4), q = i % (DDI / 4);
      int p = map_k(k, l0 + t0 + row);
      ((float4*)u_s)[i] = *(const float4*)(xc + ((size_t)b * LL + p) * DDI + q * 4);
    }
    // stage B/C tile (contiguous)
    {
      const float4* src = (const float4*)(bcb + ((size_t)bk * LL + l0 + t0) * 32);
      float4* dst = (float4*)bcs;
      for (int i = d; i < TSC * 32 / 4; i += 192) dst[i] = src[i];
    }
    __syncthreads();
    for (int tt = 0; tt < TSC; tt++) {
      float dt = dt_s[tt][d];
      float u  = u_s[tt][d];
      float dtu = dt * u;
      if (PASS == 0) sumdt += dt;
      float eA[NST];
      if (pw) {
        float E = __expf(dt * Av[0]);
        float en = 1.f;
        #pragma unroll
        for (int n = 0; n < NST; n++) { en *= E; eA[n] = en; }
      } else {
        #pragma unroll
        for (int n = 0; n < NST; n++) eA[n] = __expf(dt * Av[n]);
      }
      float y = 0.f;
      #pragma unroll
      for (int n = 0; n < NST; n++) {
        h[n] = eA[n] * h[n] + dtu * bcs[tt][n];
        y += h[n] * bcs[tt][16 + n];
      }
      if (PASS == 1) {
        int p = map_k(k, l0 + t0 + tt);
        yk[((size_t)bk * LL + p) * DDI + d] = y;
      }
    }
  }
  if (PASS == 0) {
    float* hp = hl + ((size_t)(bk * DDI + d) * NCH + ch) * NST;
    #pragma unroll
    for (int n = 0; n < NST; n++) hp[n] = h[n];
    sd[(size_t)(bk * DDI + d) * NCH + ch] = sumdt;
  }
}

// ---------------- K11b: chunk-carry propagation ----------------
__global__ __launch_bounds__(256) void k_carry(const float* __restrict__ A_logs,
    const float* __restrict__ hl, const float* __restrict__ sd, float* __restrict__ hin) {
  int idx = blockIdx.x * 256 + threadIdx.x;  // 8*192*16
  int n = idx & 15;
  int d = (idx >> 4) % DDI;
  int bk = idx / (DDI * NST);
  int k = bk & 3;
  float Aval = -__expf(A_logs[(size_t)(k * DDI + d) * NST + n]);
  float h = 0.f;
  size_t base = (size_t)(bk * DDI + d) * NCH;
  for (int ch = 0; ch < NCH; ch++) {
    hin[(base + ch) * NST + n] = h;
    h = __expf(Aval * sd[base + ch]) * h + hl[(base + ch) * NST + n];
  }
}

// ---------------- K12a: combine 4 dirs + D*u + LN(192) + silu(z) -> g ----------------
__global__ __launch_bounds__(192) void k_combine(const float* __restrict__ yk,
    const float* __restrict__ xc, const float* __restrict__ Ds, const float* __restrict__ z,
    const float* __restrict__ ong, const float* __restrict__ onb, float* __restrict__ g) {
  int pb = blockIdx.x;
  int b = pb >> 12, p = pb & (LL - 1);
  int d = threadIdx.x;
  __shared__ float red[DDI];
  __shared__ float smu, srs;
  size_t base = ((size_t)b * 4 * LL + p) * DDI + d;
  float v = yk[base] + yk[base + (size_t)LL * DDI] + yk[base + 2ul * LL * DDI] + yk[base + 3ul * LL * DDI];
  v += (Ds[d] + Ds[DDI + d] + Ds[2 * DDI + d] + Ds[3 * DDI + d]) * xc[((size_t)b * LL + p) * DDI + d];
  red[d] = v; __syncthreads();
  if (d < 64) red[d] += red[d + 128];
  __syncthreads();
  for (int s = 64; s > 0; s >>= 1) { if (d < s) red[d] += red[d + s]; __syncthreads(); }
  if (d == 0) smu = red[0] / (float)DDI;
  __syncthreads();
  float xcv = v - smu;
  red[d] = xcv * xcv; __syncthreads();
  if (d < 64) red[d] += red[d + 128];
  __syncthreads();
  for (int s = 64; s > 0; s >>= 1) { if (d < s) red[d] += red[d + s]; __syncthreads(); }
  if (d == 0) srs = rsqrtf(red[0] / (float)DDI + 1e-5f);
  __syncthreads();
  float yv = xcv * srs * ong[d] + onb[d];
  float zz = z[((size_t)b * LL + p) * DDI + d];
  g[((size_t)b * LL + p) * DDI + d] = yv * (zz / (1.f + __expf(-zz)));
}

// ---------------- K12b: out_proj (192 -> 96) -> y2 (B,96,L) ----------------
__global__ __launch_bounds__(192) void k_outproj(const float* __restrict__ g,
    const float* __restrict__ W, float* __restrict__ y2) {
  int pix0 = blockIdx.x * 32;          // over B*L
  int b = pix0 / LL, p0 = pix0 & (LL - 1);
  int tid = threadIdx.x;
  __shared__ float a[32][DDI];
  for (int t = tid; t < 32 * DDI; t += 192) a[t / DDI][t % DDI] = g[(size_t)pix0 * DDI + t];
  __syncthreads();
  int o = tid % CCH, ph = tid / CCH;
  const float* wr = W + o * DDI;
  float acc[16];
  #pragma unroll
  for (int j = 0; j < 16; j++) acc[j] = 0.f;
  for (int c = 0; c < DDI; c += 4) {
    float4 wv = *(const float4*)(wr + c);
    #pragma unroll
    for (int j = 0; j < 16; j++) {
      float4 av = *(const float4*)(&a[ph * 16 + j][c]);
      acc[j] = fmaf(av.x, wv.x, fmaf(av.y, wv.y, fmaf(av.z, wv.z, fmaf(av.w, wv.w, acc[j]))));
    }
  }
  float* base = y2 + ((size_t)b * CCH + o) * LL + p0 + ph * 16;
  #pragma unroll
  for (int jj = 0; jj < 4; jj++)
    *(float4*)(base + jj * 4) = make_float4(acc[jj * 4], acc[jj * 4 + 1], acc[jj * 4 + 2], acc[jj * 4 + 3]);
}

// ---------------- K14: recal-apply + proj 1x1 + residual ----------------
__global__ __launch_bounds__(256) void k_final(const float* __restrict__ x,
    const float* __restrict__ y2, const float* __restrict__ w2buf,
    const float* __restrict__ pw, const float* __restrict__ pb, float* __restrict__ out) {
  int idx = blockIdx.x * 256 + threadIdx.x;
  int p = idx & (LL - 1);
  int c = (idx >> 12) % CCH;
  int b = idx / (CCH * LL);
  const float* yr = y2 + (size_t)b * CCH * LL + p;
  const float* wr = pw + c * CCH;
  const float* wc = w2buf + b * CCH;
  float acc = pb[c];
  for (int o = 0; o < CCH; o++) acc += wr[o] * yr[(size_t)o * LL] * wc[o];
  out[idx] = x[idx] + acc;
}

extern "C" void kernel_launch(void* const* d_in, const int* in_sizes, int n_in,
                              void* d_out, int out_size, void* d_ws, size_t ws_size,
                              hipStream_t stream) {
  const float* x        = (const float*)d_in[0];
  const float* arf_w1   = (const float*)d_in[1];
  const float* arf_b1   = (const float*)d_in[2];
  const float* arf_w2   = (const float*)d_in[3];
  const float* arf_b2   = (const float*)d_in[4];
  const float* arf_w3   = (const float*)d_in[5];
  const float* arf_b3   = (const float*)d_in[6];
  const float* arf_w4   = (const float*)d_in[7];
  const float* arf_b4   = (const float*)d_in[8];
  const float* fuse_w   = (const float*)d_in[9];
  const float* fuse_b   = (const float*)d_in[10];
  const float* edge_w   = (const float*)d_in[11];
  const float* enh_w1   = (const float*)d_in[12];
  const float* enh_b1   = (const float*)d_in[13];
  const float* bn_g     = (const float*)d_in[14];
  const float* bn_b     = (const float*)d_in[15];
  const float* enh_w2   = (const float*)d_in[16];
  const float* enh_b2   = (const float*)d_in[17];
  const float* pre_fc1  = (const float*)d_in[18];
  const float* pre_fc2  = (const float*)d_in[19];
  const float* norm_g   = (const float*)d_in[20];
  const float* norm_b   = (const float*)d_in[21];
  const float* in_proj_w= (const float*)d_in[22];
  const float* ss_conv_w= (const float*)d_in[23];
  const float* ss_conv_b= (const float*)d_in[24];
  const float* x_proj_w = (const float*)d_in[25];
  const float* dt_w     = (const float*)d_in[26];
  const float* dt_b     = (const float*)d_in[27];
  const float* A_logs   = (const float*)d_in[28];
  const float* Ds       = (const float*)d_in[29];
  const float* out_ng   = (const float*)d_in[30];
  const float* out_nb   = (const float*)d_in[31];
  const float* out_proj_w = (const float*)d_in[32];
  const float* post_fc1 = (const float*)d_in[33];
  const float* post_fc2 = (const float*)d_in[34];
  const float* proj_w   = (const float*)d_in[35];
  const float* proj_b   = (const float*)d_in[36];

  float* ws = (float*)d_ws;
  float* fbuf  = ws + OFF_F;
  float* hbuf  = ws + OFF_H;
  float* ebuf  = ws + OFF_E;
  float* bnbuf = ws + OFF_BN;
  float* s1buf = ws + OFF_S1;
  float* w1buf = ws + OFF_W1;
  float* s2buf = ws + OFF_S2;
  float* w2buf = ws + OFF_W2;
  float* hnbuf = ws + OFF_HN;
  float* xmbuf = ws + OFF_XM;
  float* zbuf  = ws + OFF_Z;
  float* xcbuf = ws + OFF_XC;
  float* dtsbuf= ws + OFF_DTS;
  float* bcbuf = ws + OFF_BC;
  float* ykbuf = ws + OFF_YK;
  float* hlbuf = ws + OFF_HL;     // aliases F/H (dead by scan time)
  float* sdbuf = ws + OFF_SD;     // aliases E
  float* hinbuf= ws + OFF_HIN;    // aliases XM
  float* y2buf = ws + OFF_Y2;
  float* gbuf  = xmbuf;           // reuse (hin dead after pass 1)

  k_arf<<<3072, 256, 0, stream>>>(x, arf_w1, arf_b1, arf_w2, arf_b2, arf_w3, arf_b3, arf_w4, arf_b4, fbuf);
  k_fuse<<<3072, 256, 0, stream>>>(fbuf, fuse_w, fuse_b, hbuf);
  k_edge<<<3072, 256, 0, stream>>>(hbuf, edge_w, fbuf);   // edge reuses fbuf
  k_e1<<<768, 256, 0, stream>>>(fbuf, enh_w1, enh_b1, ebuf);
  k_bnstats<<<24, 256, 0, stream>>>(ebuf, bn_g, bn_b, bnbuf);
  k_enh<<<3072, 256, 0, stream>>>(ebuf, bnbuf, enh_w2, enh_b2, hbuf);
  k_rowreduce<<<192, 256, 0, stream>>>(hbuf, s1buf);
  k_recal_fc<<<2, 128, 0, stream>>>(s1buf, pre_fc1, pre_fc2, w1buf);
  k_recal_ln<<<8192, 128, 0, stream>>>(hbuf, w1buf, norm_g, norm_b, hnbuf);
  k_inproj<<<512, 384, 0, stream>>>(hnbuf, in_proj_w, xmbuf, zbuf);
  k_ssconv<<<6144, 256, 0, stream>>>(xmbuf, ss_conv_w, ss_conv_b, xcbuf);
  k_xdbl<<<dim3(LL / XT, 8), 256, 0, stream>>>(xcbuf, x_proj_w, dt_w, dt_b, dtsbuf, bcbuf);
  k_scan<0><<<dim3(NCH, 8), 192, 0, stream>>>(dtsbuf, bcbuf, xcbuf, A_logs, hlbuf, sdbuf, nullptr, nullptr);
  k_carry<<<96, 256, 0, stream>>>(A_logs, hlbuf, sdbuf, hinbuf);
  k_scan<1><<<dim3(NCH, 8), 192, 0, stream>>>(dtsbuf, bcbuf, xcbuf, A_logs, nullptr, nullptr, hinbuf, ykbuf);
  k_combine<<<8192, 192, 0, stream>>>(ykbuf, xcbuf, Ds, zbuf, out_ng, out_nb, gbuf);
  k_outproj<<<256, 192, 0, stream>>>(gbuf, out_proj_w, y2buf);
  k_rowreduce<<<192, 256, 0, stream>>>(y2buf, s2buf);
  k_recal_fc<<<2, 128, 0, stream>>>(s2buf, post_fc1, post_fc2, w2buf);
  k_final<<<3072, 256, 0, stream>>>(x, y2buf, w2buf, proj_w, proj_b, (float*)d_out);
  (void)in_sizes; (void)n_in; (void)out_size; (void)ws_size;
}

// Round 4
// 303.397 us; speedup vs baseline: 1.4677x; 1.0301x over previous
//
#include <hip/hip_runtime.h>
#include <cmath>

#define LL   4096
#define HWD  64
#define CCH  96
#define QQ   24
#define DDI  192
#define NST  16
#define NCH  64      // chunks in scan
#define CLEN 64      // steps per chunk
#define TSC  32      // steps staged per LDS tile
#define XT   64      // positions per block in k_xdbl

// ---------------- workspace layout (floats) ----------------
static const size_t OFF_F   = 0;          // 786432  f (concat arf) -> reused as edge, then hl
static const size_t OFF_H   = 786432;     // 786432  h               -> hl (upper half)
static const size_t OFF_E   = 1572864;    // 196608  e (raw)         -> sd
static const size_t OFF_BN  = 1769472;    // 64      bn scale[24], shift[24]
static const size_t OFF_S1  = 1769536;    // 192
static const size_t OFF_W1  = 1769728;    // 192
static const size_t OFF_S2  = 1769920;    // 192
static const size_t OFF_W2  = 1770112;    // 192
static const size_t OFF_HN  = 1770304;    // 786432  hn (B,L,96)
static const size_t OFF_XM  = 2556736;    // 1572864 xm (B,L,192) -> hin -> g
static const size_t OFF_Z   = 4129600;    // 1572864 z  (B,L,192)
static const size_t OFF_XC  = 5702464;    // 1572864 xc (B,L,192)
static const size_t OFF_DTS = 7275328;    // 6291456 dts (B,K,L,192)
static const size_t OFF_BC  = 13566784;   // 1048576 B|C (B,K,L,32)
static const size_t OFF_YK  = 14615360;   // 6291456 yk (B,K,L,192) at hw position
static const size_t OFF_Y2  = 22528832;   // 786432  y2 (B,96,L)
// aliases (regions dead by scan time):
static const size_t OFF_HL  = OFF_F;      // 8*192*64*16 = 1572864
static const size_t OFF_SD  = OFF_E;      // 8*192*64   = 98304
static const size_t OFF_HIN = OFF_XM;     // 1572864 (g reuses same region after pass 1)

static __device__ __forceinline__ int map_k(int k, int l) {
  int ll = (k & 2) ? (LL - 1 - l) : l;
  return (k & 1) ? (((ll & 63) << 6) | (ll >> 6)) : ll;
}

// ---------------- K1: ARF grouped dilated convs (concat f1..f4) ----------------
__global__ __launch_bounds__(256) void k_arf(const float* __restrict__ x,
    const float* __restrict__ w1, const float* __restrict__ b1,
    const float* __restrict__ w2, const float* __restrict__ b2,
    const float* __restrict__ w3, const float* __restrict__ b3,
    const float* __restrict__ w4, const float* __restrict__ b4,
    float* __restrict__ f) {
  int idx = blockIdx.x * 256 + threadIdx.x;            // B*96*L
  int p = idx & (LL - 1);
  int oc = (idx >> 12) % CCH;
  int b  = idx / (CCH * LL);
  int i = oc / QQ, q = oc % QQ;
  int dil = 1 << i;
  const float* w  = (i == 0 ? w1 : i == 1 ? w2 : i == 2 ? w3 : w4) + q * 36;
  const float* bb = (i == 0 ? b1 : i == 1 ? b2 : i == 2 ? b3 : b4);
  int yy0 = p >> 6, xx0 = p & 63;
  float acc = bb[q];
  const float* xin = x + ((size_t)b * CCH + q * 4) * LL;
  #pragma unroll
  for (int ky = 0; ky < 3; ky++) {
    int yy = yy0 + (ky - 1) * dil;
    if (yy < 0 || yy >= HWD) continue;
    #pragma unroll
    for (int kx = 0; kx < 3; kx++) {
      int xx = xx0 + (kx - 1) * dil;
      if (xx < 0 || xx >= HWD) continue;
      int pp = (yy << 6) + xx;
      #pragma unroll
      for (int ci = 0; ci < 4; ci++)
        acc += w[ci * 9 + ky * 3 + kx] * xin[(size_t)ci * LL + pp];
    }
  }
  f[idx] = acc;
}

// ---------------- K2: fuse 1x1 (96->96) ----------------
__global__ __launch_bounds__(256) void k_fuse(const float* __restrict__ f,
    const float* __restrict__ fw, const float* __restrict__ fb, float* __restrict__ h) {
  int idx = blockIdx.x * 256 + threadIdx.x;
  int p = idx & (LL - 1);
  int o = (idx >> 12) % CCH;
  int b = idx / (CCH * LL);
  const float* fr = f + (size_t)b * CCH * LL + p;
  const float* wr = fw + o * CCH;
  float acc = fb[o];
  for (int c = 0; c < CCH; c++) acc += wr[c] * fr[(size_t)c * LL];
  h[idx] = acc;
}

// ---------------- K3: depthwise 3x3 (edge) ----------------
__global__ __launch_bounds__(256) void k_edge(const float* __restrict__ h,
    const float* __restrict__ ew, float* __restrict__ edge) {
  int idx = blockIdx.x * 256 + threadIdx.x;
  int p = idx & (LL - 1);
  int c = (idx >> 12) % CCH;
  int b = idx / (CCH * LL);
  int yy0 = p >> 6, xx0 = p & 63;
  const float* w = ew + c * 9;
  const float* hr = h + ((size_t)b * CCH + c) * LL;
  float acc = 0.f;
  #pragma unroll
  for (int ky = 0; ky < 3; ky++) {
    int yy = yy0 + ky - 1;
    if (yy < 0 || yy >= HWD) continue;
    #pragma unroll
    for (int kx = 0; kx < 3; kx++) {
      int xx = xx0 + kx - 1;
      if (xx < 0 || xx >= HWD) continue;
      acc += w[ky * 3 + kx] * hr[(yy << 6) + xx];
    }
  }
  edge[idx] = acc;
}

// ---------------- K4: 1x1 96->24 ----------------
__global__ __launch_bounds__(256) void k_e1(const float* __restrict__ edge,
    const float* __restrict__ w, const float* __restrict__ bias, float* __restrict__ e) {
  int idx = blockIdx.x * 256 + threadIdx.x;         // B*24*L
  int p = idx & (LL - 1);
  int q = (idx >> 12) % QQ;
  int b = idx / (QQ * LL);
  const float* er = edge + (size_t)b * CCH * LL + p;
  const float* wr = w + q * CCH;
  float acc = bias[q];
  for (int c = 0; c < CCH; c++) acc += wr[c] * er[(size_t)c * LL];
  e[idx] = acc;
}

// ---------------- K5: BN stats over (B,H,W) per channel ----------------
__global__ __launch_bounds__(256) void k_bnstats(const float* __restrict__ e,
    const float* __restrict__ g, const float* __restrict__ bb, float* __restrict__ bn) {
  int q = blockIdx.x, tid = threadIdx.x;
  __shared__ float rs[256], r2[256];
  float s = 0.f, s2 = 0.f;
  for (int b = 0; b < 2; b++) {
    const float* er = e + ((size_t)b * QQ + q) * LL;
    for (int p = tid; p < LL; p += 256) { float v = er[p]; s += v; s2 += v * v; }
  }
  rs[tid] = s; r2[tid] = s2; __syncthreads();
  for (int st = 128; st > 0; st >>= 1) {
    if (tid < st) { rs[tid] += rs[tid + st]; r2[tid] += r2[tid + st]; }
    __syncthreads();
  }
  if (tid == 0) {
    float mu = rs[0] / (2.f * LL);
    float var = r2[0] / (2.f * LL) - mu * mu;
    float sc = g[q] * rsqrtf(var + 1e-5f);
    bn[q] = sc;
    bn[QQ + q] = bb[q] - mu * sc;
  }
}

// ---------------- K6: enh 1x1 24->96, sigmoid gate, h *= (1+sig) ----------------
__global__ __launch_bounds__(256) void k_enh(const float* __restrict__ e,
    const float* __restrict__ bn, const float* __restrict__ w2,
    const float* __restrict__ b2, float* __restrict__ h) {
  int idx = blockIdx.x * 256 + threadIdx.x;
  int p = idx & (LL - 1);
  int o = (idx >> 12) % CCH;
  int b = idx / (CCH * LL);
  const float* er = e + (size_t)b * QQ * LL + p;
  const float* wr = w2 + o * QQ;
  float acc = b2[o];
  #pragma unroll
  for (int q = 0; q < QQ; q++) {
    float en = fmaxf(er[(size_t)q * LL] * bn[q] + bn[QQ + q], 0.f);
    acc += wr[q] * en;
  }
  float sig = 1.f / (1.f + __expf(-acc));
  h[idx] *= (1.f + sig);
}

// ---------------- K7a: per-(b,c) mean+max over L ----------------
__global__ __launch_bounds__(256) void k_rowreduce(const float* __restrict__ t, float* __restrict__ sout) {
  int row = blockIdx.x, tid = threadIdx.x;   // row = b*96+c
  __shared__ float rs[256], rm[256];
  float s = 0.f, m = -3.402823466e38f;
  const float* tr = t + (size_t)row * LL;
  for (int p = tid; p < LL; p += 256) { float v = tr[p]; s += v; m = fmaxf(m, v); }
  rs[tid] = s; rm[tid] = m; __syncthreads();
  for (int st = 128; st > 0; st >>= 1) {
    if (tid < st) { rs[tid] += rs[tid + st]; rm[tid] = fmaxf(rm[tid], rm[tid + st]); }
    __syncthreads();
  }
  if (tid == 0) sout[row] = rs[0] / (float)LL + rm[0];
}

// ---------------- K7b: channel-recal tiny FC ----------------
__global__ __launch_bounds__(128) void k_recal_fc(const float* __restrict__ s1,
    const float* __restrict__ fc1, const float* __restrict__ fc2, float* __restrict__ wout) {
  int b = blockIdx.x, tid = threadIdx.x;
  __shared__ float sv[CCH];
  __shared__ float hid[QQ];
  if (tid < CCH) sv[tid] = s1[b * CCH + tid];
  __syncthreads();
  if (tid < QQ) {
    float a = 0.f;
    for (int c = 0; c < CCH; c++) a += sv[c] * fc1[tid * CCH + c];
    hid[tid] = fmaxf(a, 0.f);
  }
  __syncthreads();
  if (tid < CCH) {
    float a = 0.f;
    #pragma unroll
    for (int q = 0; q < QQ; q++) a += hid[q] * fc2[tid * QQ + q];
    wout[b * CCH + tid] = 1.f / (1.f + __expf(-a));
  }
}

// ---------------- K8a: apply recal + LayerNorm(C=96) -> hn (B,L,96) ----------------
__global__ __launch_bounds__(128) void k_recal_ln(const float* __restrict__ h,
    const float* __restrict__ w1buf, const float* __restrict__ ng,
    const float* __restrict__ nb, float* __restrict__ hn) {
  int pb = blockIdx.x;                 // b*L+p
  int b = pb >> 12, p = pb & (LL - 1);
  int tid = threadIdx.x;
  __shared__ float red[128];
  __shared__ float smu, srs;
  float v = 0.f;
  if (tid < CCH) v = h[((size_t)b * CCH + tid) * LL + p] * w1buf[b * CCH + tid];
  red[tid] = v; __syncthreads();
  for (int s = 64; s > 0; s >>= 1) { if (tid < s) red[tid] += red[tid + s]; __syncthreads(); }
  if (tid == 0) smu = red[0] / (float)CCH;
  __syncthreads();
  float xcv = (tid < CCH) ? v - smu : 0.f;
  red[tid] = xcv * xcv; __syncthreads();
  for (int s = 64; s > 0; s >>= 1) { if (tid < s) red[tid] += red[tid + s]; __syncthreads(); }
  if (tid == 0) srs = rsqrtf(red[0] / (float)CCH + 1e-5f);
  __syncthreads();
  if (tid < CCH) hn[((size_t)b * LL + p) * CCH + tid] = xcv * srs * ng[tid] + nb[tid];
}

// ---------------- K8b: in_proj (96 -> 384), split xm/z ----------------
__global__ __launch_bounds__(384) void k_inproj(const float* __restrict__ hn,
    const float* __restrict__ W, float* __restrict__ xm, float* __restrict__ z) {
  int pix0 = blockIdx.x * 16;          // over B*L
  int tid = threadIdx.x;
  __shared__ float a[16][CCH];
  for (int t = tid; t < 16 * CCH; t += 384) a[t / CCH][t % CCH] = hn[(size_t)pix0 * CCH + t];
  __syncthreads();
  const float* wr = W + tid * CCH;
  float acc[16];
  #pragma unroll
  for (int j = 0; j < 16; j++) acc[j] = 0.f;
  for (int c = 0; c < CCH; c += 4) {
    float4 wv = *(const float4*)(wr + c);
    #pragma unroll
    for (int j = 0; j < 16; j++) {
      float4 av = *(const float4*)(&a[j][c]);
      acc[j] = fmaf(av.x, wv.x, fmaf(av.y, wv.y, fmaf(av.z, wv.z, fmaf(av.w, wv.w, acc[j]))));
    }
  }
  float* dst = (tid < DDI) ? xm : z;
  int oo = (tid < DDI) ? tid : tid - DDI;
  #pragma unroll
  for (int j = 0; j < 16; j++) dst[(size_t)(pix0 + j) * DDI + oo] = acc[j];
}

// ---------------- K9: depthwise 3x3 on xm + bias + silu -> xc ----------------
__global__ __launch_bounds__(256) void k_ssconv(const float* __restrict__ xm,
    const float* __restrict__ w, const float* __restrict__ bias, float* __restrict__ xc) {
  int idx = blockIdx.x * 256 + threadIdx.x;      // B*L*192, d fastest
  int d = idx % DDI;
  int p = (idx / DDI) & (LL - 1);
  int b = idx / (DDI * LL);
  int yy0 = p >> 6, xx0 = p & 63;
  float acc = bias[d];
  const float* wr = w + d * 9;
  const float* xr = xm + (size_t)b * LL * DDI + d;
  #pragma unroll
  for (int ky = 0; ky < 3; ky++) {
    int yy = yy0 + ky - 1;
    if (yy < 0 || yy >= HWD) continue;
    #pragma unroll
    for (int kx = 0; kx < 3; kx++) {
      int xx = xx0 + kx - 1;
      if (xx < 0 || xx >= HWD) continue;
      acc += wr[ky * 3 + kx] * xr[(size_t)((yy << 6) + xx) * DDI];
    }
  }
  xc[(size_t)idx] = acc / (1.f + __expf(-acc));
}

// ---------------- K10: x_proj (192->38) + dt proj (6->192) + softplus ----------------
// lanes = positions, weights staged in two 19-row halves for occupancy (2 blocks/CU)
__global__ __launch_bounds__(256) void k_xdbl(const float* __restrict__ xc,
    const float* __restrict__ xpw, const float* __restrict__ dtw,
    const float* __restrict__ dtb, float* __restrict__ dts, float* __restrict__ bcb) {
  int lt = blockIdx.x;                 // LL/XT tiles
  int bk = blockIdx.y;                 // b*4+k
  int b = bk >> 2, k = bk & 3;
  int t = threadIdx.x;
  __shared__ float xs[XT][196];        // 50.2 KB
  __shared__ float wbuf[19 * 192];     // 14.6 KB, one c-half at a time
  __shared__ float dtr[XT][6];         // 1.5 KB
  int l0 = lt * XT;
  // stage x tile (rows contiguous 768B regardless of direction)
  for (int i = t; i < XT * 48; i += 256) {
    int li = i / 48, dq = i % 48;
    int p = map_k(k, l0 + li);
    *(float4*)(&xs[li][dq * 4]) = *(const float4*)(xc + ((size_t)b * LL + p) * DDI + dq * 4);
  }
  int li = t & 63, cg = t >> 6;        // lane = position, wave-uniform c-group
  for (int h = 0; h < 2; h++) {
    int c0 = h * 19;
    __syncthreads();                   // xs staged / previous wbuf reads done
    {
      const float4* src = (const float4*)(xpw + ((size_t)k * 38 + c0) * DDI);
      float4* dst = (float4*)wbuf;
      for (int i = t; i < 19 * 48; i += 256) dst[i] = src[i];
    }
    __syncthreads();
    float acc[5];
    #pragma unroll
    for (int j = 0; j < 5; j++) acc[j] = 0.f;
    for (int dq = 0; dq < 48; dq++) {
      float4 xv = *(const float4*)(&xs[li][dq * 4]);
      #pragma unroll
      for (int j = 0; j < 5; j++) {
        int cc = cg + 4 * j;
        if (cc < 19) {
          float4 wv = *(const float4*)(&wbuf[cc * DDI + dq * 4]);  // uniform broadcast
          acc[j] = fmaf(xv.x, wv.x, fmaf(xv.y, wv.y, fmaf(xv.z, wv.z, fmaf(xv.w, wv.w, acc[j]))));
        }
      }
    }
    #pragma unroll
    for (int j = 0; j < 5; j++) {
      int cc = cg + 4 * j;
      if (cc >= 19) continue;
      int c = c0 + cc;
      if (c < 6) dtr[li][c] = acc[j];
      else bcb[((size_t)bk * LL + l0 + li) * 32 + (c - 6)] = acc[j];
    }
  }
  __syncthreads();
  // phase 2: dt projection (6 -> 192) + softplus
  for (int i = t; i < XT * DDI; i += 256) {
    int lp = i / DDI, dd = i % DDI;
    const float* wr = dtw + (size_t)(k * DDI + dd) * 6;
    float a = dtb[k * DDI + dd];
    #pragma unroll
    for (int r = 0; r < 6; r++) a = fmaf(wr[r], dtr[lp][r], a);
    float sp = (a > 15.f) ? a : __logf(1.f + __expf(a));
    dts[((size_t)bk * LL + l0 + lp) * DDI + dd] = sp;
  }
}

// ---------------- K11: chunked selective scan (LDS-staged tiles) ----------------
template <int PASS>
__global__ __launch_bounds__(192) void k_scan(const float* __restrict__ dts,
    const float* __restrict__ bcb, const float* __restrict__ xc,
    const float* __restrict__ A_logs, float* __restrict__ hl, float* __restrict__ sd,
    const float* __restrict__ hin, float* __restrict__ yk) {
  int ch = blockIdx.x, bk = blockIdx.y;
  int b = bk >> 2, k = bk & 3;
  int d = threadIdx.x;
  __shared__ float dt_s[TSC][DDI];     // 24 KB
  __shared__ float u_s[TSC][DDI];      // 24 KB
  __shared__ float bcs[TSC][32];       // 4 KB
  float Av[NST];
  #pragma unroll
  for (int n = 0; n < NST; n++) Av[n] = -__expf(A_logs[(size_t)(k * DDI + d) * NST + n]);
  bool pw = true;
  #pragma unroll
  for (int n = 1; n < NST; n++) pw = pw && (fabsf(Av[n] - (float)(n + 1) * Av[0]) <= 1e-3f * (n + 1));
  float h[NST];
  if (PASS == 0) {
    #pragma unroll
    for (int n = 0; n < NST; n++) h[n] = 0.f;
  } else {
    const float* hp = hin + ((size_t)(bk * DDI + d) * NCH + ch) * NST;
    #pragma unroll
    for (int n = 0; n < NST; n++) h[n] = hp[n];
  }
  float sumdt = 0.f;
  int l0 = ch * CLEN;
  for (int t0 = 0; t0 < CLEN; t0 += TSC) {
    __syncthreads();
    {
      const float4* src = (const float4*)(dts + ((size_t)bk * LL + l0 + t0) * DDI);
      float4* dst = (float4*)dt_s;
      for (int i = d; i < TSC * DDI / 4; i += 192) dst[i] = src[i];
    }
    for (int i = d; i < TSC * (DDI / 4); i += 192) {
      int row = i / (DDI / 4), q = i % (DDI / 4);
      int p = map_k(k, l0 + t0 + row);
      ((float4*)u_s)[i] = *(const float4*)(xc + ((size_t)b * LL + p) * DDI + q * 4);
    }
    {
      const float4* src = (const float4*)(bcb + ((size_t)bk * LL + l0 + t0) * 32);
      float4* dst = (float4*)bcs;
      for (int i = d; i < TSC * 32 / 4; i += 192) dst[i] = src[i];
    }
    __syncthreads();
    for (int tt = 0; tt < TSC; tt++) {
      float dt = dt_s[tt][d];
      float u  = u_s[tt][d];
      float dtu = dt * u;
      if (PASS == 0) sumdt += dt;
      float eA[NST];
      if (pw) {
        float E = __expf(dt * Av[0]);
        float en = 1.f;
        #pragma unroll
        for (int n = 0; n < NST; n++) { en *= E; eA[n] = en; }
      } else {
        #pragma unroll
        for (int n = 0; n < NST; n++) eA[n] = __expf(dt * Av[n]);
      }
      float y = 0.f;
      #pragma unroll
      for (int n = 0; n < NST; n++) {
        h[n] = eA[n] * h[n] + dtu * bcs[tt][n];
        y += h[n] * bcs[tt][16 + n];
      }
      if (PASS == 1) {
        int p = map_k(k, l0 + t0 + tt);
        yk[((size_t)bk * LL + p) * DDI + d] = y;
      }
    }
  }
  if (PASS == 0) {
    float* hp = hl + ((size_t)(bk * DDI + d) * NCH + ch) * NST;
    #pragma unroll
    for (int n = 0; n < NST; n++) hp[n] = h[n];
    sd[(size_t)(bk * DDI + d) * NCH + ch] = sumdt;
  }
}

// ---------------- K11b: chunk-carry propagation ----------------
__global__ __launch_bounds__(256) void k_carry(const float* __restrict__ A_logs,
    const float* __restrict__ hl, const float* __restrict__ sd, float* __restrict__ hin) {
  int idx = blockIdx.x * 256 + threadIdx.x;  // 8*192*16
  int n = idx & 15;
  int d = (idx >> 4) % DDI;
  int bk = idx / (DDI * NST);
  int k = bk & 3;
  float Aval = -__expf(A_logs[(size_t)(k * DDI + d) * NST + n]);
  float h = 0.f;
  size_t base = (size_t)(bk * DDI + d) * NCH;
  for (int ch = 0; ch < NCH; ch++) {
    hin[(base + ch) * NST + n] = h;
    h = __expf(Aval * sd[base + ch]) * h + hl[(base + ch) * NST + n];
  }
}

// ---------------- K12a: combine 4 dirs + D*u + LN(192) + silu(z) -> g ----------------
__global__ __launch_bounds__(192) void k_combine(const float* __restrict__ yk,
    const float* __restrict__ xc, const float* __restrict__ Ds, const float* __restrict__ z,
    const float* __restrict__ ong, const float* __restrict__ onb, float* __restrict__ g) {
  int pb = blockIdx.x;
  int b = pb >> 12, p = pb & (LL - 1);
  int d = threadIdx.x;
  __shared__ float red[DDI];
  __shared__ float smu, srs;
  size_t base = ((size_t)b * 4 * LL + p) * DDI + d;
  float v = yk[base] + yk[base + (size_t)LL * DDI] + yk[base + 2ul * LL * DDI] + yk[base + 3ul * LL * DDI];
  v += (Ds[d] + Ds[DDI + d] + Ds[2 * DDI + d] + Ds[3 * DDI + d]) * xc[((size_t)b * LL + p) * DDI + d];
  red[d] = v; __syncthreads();
  if (d < 64) red[d] += red[d + 128];
  __syncthreads();
  for (int s = 64; s > 0; s >>= 1) { if (d < s) red[d] += red[d + s]; __syncthreads(); }
  if (d == 0) smu = red[0] / (float)DDI;
  __syncthreads();
  float xcv = v - smu;
  red[d] = xcv * xcv; __syncthreads();
  if (d < 64) red[d] += red[d + 128];
  __syncthreads();
  for (int s = 64; s > 0; s >>= 1) { if (d < s) red[d] += red[d + s]; __syncthreads(); }
  if (d == 0) srs = rsqrtf(red[0] / (float)DDI + 1e-5f);
  __syncthreads();
  float yv = xcv * srs * ong[d] + onb[d];
  float zz = z[((size_t)b * LL + p) * DDI + d];
  g[((size_t)b * LL + p) * DDI + d] = yv * (zz / (1.f + __expf(-zz)));
}

// ---------------- K12b: out_proj (192 -> 96) -> y2 (B,96,L) ----------------
__global__ __launch_bounds__(192) void k_outproj(const float* __restrict__ g,
    const float* __restrict__ W, float* __restrict__ y2) {
  int pix0 = blockIdx.x * 32;          // over B*L
  int b = pix0 / LL, p0 = pix0 & (LL - 1);
  int tid = threadIdx.x;
  __shared__ float a[32][DDI];
  for (int t = tid; t < 32 * DDI; t += 192) a[t / DDI][t % DDI] = g[(size_t)pix0 * DDI + t];
  __syncthreads();
  int o = tid % CCH, ph = tid / CCH;
  const float* wr = W + o * DDI;
  float acc[16];
  #pragma unroll
  for (int j = 0; j < 16; j++) acc[j] = 0.f;
  for (int c = 0; c < DDI; c += 4) {
    float4 wv = *(const float4*)(wr + c);
    #pragma unroll
    for (int j = 0; j < 16; j++) {
      float4 av = *(const float4*)(&a[ph * 16 + j][c]);
      acc[j] = fmaf(av.x, wv.x, fmaf(av.y, wv.y, fmaf(av.z, wv.z, fmaf(av.w, wv.w, acc[j]))));
    }
  }
  float* base = y2 + ((size_t)b * CCH + o) * LL + p0 + ph * 16;
  #pragma unroll
  for (int jj = 0; jj < 4; jj++)
    *(float4*)(base + jj * 4) = make_float4(acc[jj * 4], acc[jj * 4 + 1], acc[jj * 4 + 2], acc[jj * 4 + 3]);
}

// ---------------- K14: recal-apply + proj 1x1 + residual ----------------
__global__ __launch_bounds__(256) void k_final(const float* __restrict__ x,
    const float* __restrict__ y2, const float* __restrict__ w2buf,
    const float* __restrict__ pw, const float* __restrict__ pb, float* __restrict__ out) {
  int idx = blockIdx.x * 256 + threadIdx.x;
  int p = idx & (LL - 1);
  int c = (idx >> 12) % CCH;
  int b = idx / (CCH * LL);
  const float* yr = y2 + (size_t)b * CCH * LL + p;
  const float* wr = pw + c * CCH;
  const float* wc = w2buf + b * CCH;
  float acc = pb[c];
  for (int o = 0; o < CCH; o++) acc += wr[o] * yr[(size_t)o * LL] * wc[o];
  out[idx] = x[idx] + acc;
}

extern "C" void kernel_launch(void* const* d_in, const int* in_sizes, int n_in,
                              void* d_out, int out_size, void* d_ws, size_t ws_size,
                              hipStream_t stream) {
  const float* x        = (const float*)d_in[0];
  const float* arf_w1   = (const float*)d_in[1];
  const float* arf_b1   = (const float*)d_in[2];
  const float* arf_w2   = (const float*)d_in[3];
  const float* arf_b2   = (const float*)d_in[4];
  const float* arf_w3   = (const float*)d_in[5];
  const float* arf_b3   = (const float*)d_in[6];
  const float* arf_w4   = (const float*)d_in[7];
  const float* arf_b4   = (const float*)d_in[8];
  const float* fuse_w   = (const float*)d_in[9];
  const float* fuse_b   = (const float*)d_in[10];
  const float* edge_w   = (const float*)d_in[11];
  const float* enh_w1   = (const float*)d_in[12];
  const float* enh_b1   = (const float*)d_in[13];
  const float* bn_g     = (const float*)d_in[14];
  const float* bn_b     = (const float*)d_in[15];
  const float* enh_w2   = (const float*)d_in[16];
  const float* enh_b2   = (const float*)d_in[17];
  const float* pre_fc1  = (const float*)d_in[18];
  const float* pre_fc2  = (const float*)d_in[19];
  const float* norm_g   = (const float*)d_in[20];
  const float* norm_b   = (const float*)d_in[21];
  const float* in_proj_w= (const float*)d_in[22];
  const float* ss_conv_w= (const float*)d_in[23];
  const float* ss_conv_b= (const float*)d_in[24];
  const float* x_proj_w = (const float*)d_in[25];
  const float* dt_w     = (const float*)d_in[26];
  const float* dt_b     = (const float*)d_in[27];
  const float* A_logs   = (const float*)d_in[28];
  const float* Ds       = (const float*)d_in[29];
  const float* out_ng   = (const float*)d_in[30];
  const float* out_nb   = (const float*)d_in[31];
  const float* out_proj_w = (const float*)d_in[32];
  const float* post_fc1 = (const float*)d_in[33];
  const float* post_fc2 = (const float*)d_in[34];
  const float* proj_w   = (const float*)d_in[35];
  const float* proj_b   = (const float*)d_in[36];

  float* ws = (float*)d_ws;
  float* fbuf  = ws + OFF_F;
  float* hbuf  = ws + OFF_H;
  float* ebuf  = ws + OFF_E;
  float* bnbuf = ws + OFF_BN;
  float* s1buf = ws + OFF_S1;
  float* w1buf = ws + OFF_W1;
  float* s2buf = ws + OFF_S2;
  float* w2buf = ws + OFF_W2;
  float* hnbuf = ws + OFF_HN;
  float* xmbuf = ws + OFF_XM;
  float* zbuf  = ws + OFF_Z;
  float* xcbuf = ws + OFF_XC;
  float* dtsbuf= ws + OFF_DTS;
  float* bcbuf = ws + OFF_BC;
  float* ykbuf = ws + OFF_YK;
  float* hlbuf = ws + OFF_HL;     // aliases F/H (dead by scan time)
  float* sdbuf = ws + OFF_SD;     // aliases E
  float* hinbuf= ws + OFF_HIN;    // aliases XM
  float* y2buf = ws + OFF_Y2;
  float* gbuf  = xmbuf;           // reuse (hin dead after pass 1)

  k_arf<<<3072, 256, 0, stream>>>(x, arf_w1, arf_b1, arf_w2, arf_b2, arf_w3, arf_b3, arf_w4, arf_b4, fbuf);
  k_fuse<<<3072, 256, 0, stream>>>(fbuf, fuse_w, fuse_b, hbuf);
  k_edge<<<3072, 256, 0, stream>>>(hbuf, edge_w, fbuf);   // edge reuses fbuf
  k_e1<<<768, 256, 0, stream>>>(fbuf, enh_w1, enh_b1, ebuf);
  k_bnstats<<<24, 256, 0, stream>>>(ebuf, bn_g, bn_b, bnbuf);
  k_enh<<<3072, 256, 0, stream>>>(ebuf, bnbuf, enh_w2, enh_b2, hbuf);
  k_rowreduce<<<192, 256, 0, stream>>>(hbuf, s1buf);
  k_recal_fc<<<2, 128, 0, stream>>>(s1buf, pre_fc1, pre_fc2, w1buf);
  k_recal_ln<<<8192, 128, 0, stream>>>(hbuf, w1buf, norm_g, norm_b, hnbuf);
  k_inproj<<<512, 384, 0, stream>>>(hnbuf, in_proj_w, xmbuf, zbuf);
  k_ssconv<<<6144, 256, 0, stream>>>(xmbuf, ss_conv_w, ss_conv_b, xcbuf);
  k_xdbl<<<dim3(LL / XT, 8), 256, 0, stream>>>(xcbuf, x_proj_w, dt_w, dt_b, dtsbuf, bcbuf);
  k_scan<0><<<dim3(NCH, 8), 192, 0, stream>>>(dtsbuf, bcbuf, xcbuf, A_logs, hlbuf, sdbuf, nullptr, nullptr);
  k_carry<<<96, 256, 0, stream>>>(A_logs, hlbuf, sdbuf, hinbuf);
  k_scan<1><<<dim3(NCH, 8), 192, 0, stream>>>(dtsbuf, bcbuf, xcbuf, A_logs, nullptr, nullptr, hinbuf, ykbuf);
  k_combine<<<8192, 192, 0, stream>>>(ykbuf, xcbuf, Ds, zbuf, out_ng, out_nb, gbuf);
  k_outproj<<<256, 192, 0, stream>>>(gbuf, out_proj_w, y2buf);
  k_rowreduce<<<192, 256, 0, stream>>>(y2buf, s2buf);
  k_recal_fc<<<2, 128, 0, stream>>>(s2buf, post_fc1, post_fc2, w2buf);
  k_final<<<3072, 256, 0, stream>>>(x, y2buf, w2buf, proj_w, proj_b, (float*)d_out);
  (void)in_sizes; (void)n_in; (void)out_size; (void)ws_size;
}